// Round 15
// baseline (182.518 us; speedup 1.0000x reference)
//
#include <hip/hip_runtime.h>

#define NN 100000
#define NE 1600000
#define D 64
#define NR 8
#define TS 16                  // dst-tile size (nodes per block)
#define NT (NN / TS)           // 6250 tiles, exact
#define APAD 68                // accum row pad (floats)
#define RPAD 17                // reduction scratch pad
#define NB 128                 // (r, dst&15) bins per tile
#define CAP 512                // slots per tile segment
#define SUBN 4                 // sub-cursors per tile
#define CAPSUB 128             // slots per sub-segment (mean 64, 8 sigma)
#define CSTRIDE 16             // cursor padding: 1 cursor per 64B line
#define SCHUNK 2048            // edges per scatter block
#define NCH ((NE + SCHUNK - 1) / SCHUNK)   // 782
#define TPS ((NT + 7) / 8)     // tiles per slice: 782
#define NWPK 4096              // W bf16-frag entries (8r x 2ks x 4g x 64col)
#define NWPKR 512              // Wr entries (2ks x 4g x 64col)
#define XPB 12500              // xpack blocks (NN*D/2 / 256)
#define PPB 18                 // prepack blocks
#define SCB (NCH * 8)          // scatter blocks: 6256

typedef short bf16x8 __attribute__((ext_vector_type(8)));
typedef float f32x4 __attribute__((ext_vector_type(4)));

// f32 -> bf16 round-to-nearest-even (finite inputs only)
__device__ __forceinline__ unsigned f2bfu(float f) {
    unsigned u = __float_as_uint(f);
    return (u + 0x7fffu + ((u >> 16) & 1u)) >> 16;
}
__device__ __forceinline__ short f2bf(float f) { return (short)f2bfu(f); }
__device__ __forceinline__ unsigned pk2(float a, float b) {
    return (f2bfu(a) & 0xffffu) | (f2bfu(b) << 16);
}

__global__ void init_kernel(int* __restrict__ cursor) {
    int i = blockIdx.x * blockDim.x + threadIdx.x;   // i = tile*SUBN+sub
    if (i < NT * SUBN)
        cursor[(size_t)i * CSTRIDE] = (i >> 2) * CAP + (i & 3) * CAPSUB;
}

// Mega kernel: [0,SCB) sliced scatter | [SCB,+XPB) xpack | [+PPB) prepack.
// Scatter: slice = blockIdx&7 (XCD-pinned), sub-cursor = (blockIdx>>3)&3 —
// 4x more cursor lines -> 4x fewer serialized RMWs per line.
__global__ void __launch_bounds__(256) mega_kernel(
    const int* __restrict__ ei, const int* __restrict__ et,
    const float* __restrict__ x, const float* __restrict__ W,
    const float* __restrict__ Wr, int* __restrict__ cursor,
    int* __restrict__ sorted, unsigned* __restrict__ xb,
    uint4* __restrict__ wpk)
{
    const int b = blockIdx.x;
    const int tid = threadIdx.x;
    if (b < SCB) {
        const int s8 = b & 7;
        const int sub = (b >> 3) & 3;
        const int c0 = (b >> 3) * SCHUNK;
        const int tlo = s8 * TPS;
        const int thi = min(tlo + TPS, NT);
        int d_[8], t_[8];
        bool keep[8];
#pragma unroll
        for (int k = 0; k < 8; ++k) {
            int e = c0 + tid + k * 256;
            d_[k] = (e < NE) ? ei[NE + e] : -1;
            t_[k] = d_[k] >> 4;
            keep[k] = (d_[k] >= 0) && (t_[k] >= tlo) && (t_[k] < thi);
        }
        int s_[8], r_[8];
#pragma unroll
        for (int k = 0; k < 8; ++k) {
            int e = c0 + tid + k * 256;
            s_[k] = keep[k] ? ei[e] : 0;
            r_[k] = keep[k] ? et[e] : 0;
        }
        int pos[8];
#pragma unroll
        for (int k = 0; k < 8; ++k)
            if (keep[k])
                pos[k] = atomicAdd(&cursor[((size_t)t_[k] * SUBN + sub) * CSTRIDE], 1);
#pragma unroll
        for (int k = 0; k < 8; ++k)
            if (keep[k] && pos[k] < t_[k] * CAP + sub * CAPSUB + CAPSUB)
                sorted[pos[k]] = s_[k] | (r_[k] << 17) | ((d_[k] & 15) << 20);
    } else if (b < SCB + XPB) {
        int i = (b - SCB) * 256 + tid;          // < NN*D/2 exactly
        float2 f = ((const float2*)x)[i];
        xb[i] = pk2(f.x, f.y);
    } else {
        int e = (b - SCB - XPB) * 256 + tid;
        if (e >= NWPK + NWPKR) return;
        const float* src;
        int col, row0;
        if (e < NWPK) {
            int r = e >> 9, ks = (e >> 8) & 1, g = (e >> 6) & 3;
            col = e & 63;
            src = W + (size_t)r * D * D;
            row0 = ks * 32 + g * 8;
        } else {
            int e2 = e - NWPK;
            int ks = (e2 >> 8) & 1, g = (e2 >> 6) & 3;
            col = e2 & 63;
            src = Wr;
            row0 = ks * 32 + g * 8;
        }
        float v[8];
#pragma unroll
        for (int j = 0; j < 8; ++j) v[j] = src[(size_t)(row0 + j) * D + col];
        uint4 o;
        o.x = pk2(v[0], v[1]); o.y = pk2(v[2], v[3]);
        o.z = pk2(v[4], v[5]); o.w = pk2(v[6], v[7]);
        wpk[e] = o;
    }
}

// One block (8 waves, 512 thr) per dst-tile. Single-pass:
// Stage 1: load 4 sub-segments (thread tid -> sub=tid>>7, idx=tid&127),
//          in-LDS counting sort by bin=(r*16+t), wave-0 shfl prefix scan.
// Stage 2: 16-lane groups walk their 4 owned bins INTERLEAVED (4 independent
//          load chains), f32 register accumulate, pure-write LDS flush.
// Stage 2.5: in-place mean-scale + f32->bf16 pack (count from bh).
// Stage 3: MFMA (1 ds_read + 1 vmem per MFMA); halves reduced via LDS.
__global__ void __launch_bounds__(512) fused_kernel(
    const float* __restrict__ x, const unsigned* __restrict__ xb,
    const int* __restrict__ sorted, const int* __restrict__ cursor,
    const uint4* __restrict__ wpk, const float* __restrict__ bias,
    float* __restrict__ out)
{
    __shared__ float accum[NR * TS * APAD];   // rows indexed by bin=r*16+t
    __shared__ int eseq[CAP];
    __shared__ int bh[NB], bst[NB], bcur[NB];
    const int tid = threadIdx.x;
    const int lane = tid & 63;
    const int wv = tid >> 6;          // 0..7
    const int grp = tid >> 4;         // 0..31
    const int q = tid & 15;           // 8B slot in row
    const int tile = blockIdx.x;

    const int sub = tid >> 7;         // 0..3
    const int idx = tid & 127;
    int cnt_s = cursor[((size_t)tile * SUBN + sub) * CSTRIDE]
              - (tile * CAP + sub * CAPSUB);
    if (tid < NB) bh[tid] = 0;
    __syncthreads();

    cnt_s = min(max(cnt_s, 0), CAPSUB);
    int rec = 0, bin = 0;
    const bool have = idx < cnt_s;
    if (have) {
        rec = sorted[tile * CAP + sub * CAPSUB + idx];
        bin = ((rec >> 17) & 7) * 16 + ((rec >> 20) & 15);
        atomicAdd(&bh[bin], 1);
    }
    __syncthreads();
    if (wv == 0) {                     // parallel 128-bin exclusive scan
        int b0 = bh[2 * lane], b1 = bh[2 * lane + 1];
        int s = b0 + b1;
        int inc = s;
#pragma unroll
        for (int off = 1; off < 64; off <<= 1) {
            int u = __shfl_up(inc, off);
            if (lane >= off) inc += u;
        }
        int excl = inc - s;
        bst[2 * lane] = excl;          bcur[2 * lane] = excl;
        bst[2 * lane + 1] = excl + b0; bcur[2 * lane + 1] = excl + b0;
    }
    __syncthreads();
    if (have) {
        int p = atomicAdd(&bcur[bin], 1);
        eseq[p] = rec;
    }
    __syncthreads();
    {
        // 4 owned bins walked in lockstep: 4 independent gather chains
        const int b0 = grp, b1 = grp + 32, b2 = grp + 64, b3 = grp + 96;
        const int m0 = bh[b0], m1 = bh[b1], m2 = bh[b2], m3 = bh[b3];
        const int s0 = bst[b0], s1 = bst[b1], s2 = bst[b2], s3 = bst[b3];
        float a0x=0.f,a0y=0.f,a0z=0.f,a0w=0.f;
        float a1x=0.f,a1y=0.f,a1z=0.f,a1w=0.f;
        float a2x=0.f,a2y=0.f,a2z=0.f,a2w=0.f;
        float a3x=0.f,a3y=0.f,a3z=0.f,a3w=0.f;
        int mm = max(max(m0, m1), max(m2, m3));
        for (int i = 0; i < mm; ++i) {
            if (i < m0) {
                int s = eseq[s0 + i] & 0x1FFFF; if (s >= NN) s = 0;
                uint2 v = *(const uint2*)(xb + (size_t)s * (D / 2) + q * 2);
                a0x += __uint_as_float(v.x << 16);
                a0y += __uint_as_float(v.x & 0xffff0000u);
                a0z += __uint_as_float(v.y << 16);
                a0w += __uint_as_float(v.y & 0xffff0000u);
            }
            if (i < m1) {
                int s = eseq[s1 + i] & 0x1FFFF; if (s >= NN) s = 0;
                uint2 v = *(const uint2*)(xb + (size_t)s * (D / 2) + q * 2);
                a1x += __uint_as_float(v.x << 16);
                a1y += __uint_as_float(v.x & 0xffff0000u);
                a1z += __uint_as_float(v.y << 16);
                a1w += __uint_as_float(v.y & 0xffff0000u);
            }
            if (i < m2) {
                int s = eseq[s2 + i] & 0x1FFFF; if (s >= NN) s = 0;
                uint2 v = *(const uint2*)(xb + (size_t)s * (D / 2) + q * 2);
                a2x += __uint_as_float(v.x << 16);
                a2y += __uint_as_float(v.x & 0xffff0000u);
                a2z += __uint_as_float(v.y << 16);
                a2w += __uint_as_float(v.y & 0xffff0000u);
            }
            if (i < m3) {
                int s = eseq[s3 + i] & 0x1FFFF; if (s >= NN) s = 0;
                uint2 v = *(const uint2*)(xb + (size_t)s * (D / 2) + q * 2);
                a3x += __uint_as_float(v.x << 16);
                a3y += __uint_as_float(v.x & 0xffff0000u);
                a3z += __uint_as_float(v.y << 16);
                a3w += __uint_as_float(v.y & 0xffff0000u);
            }
        }
        float* p0 = &accum[b0 * APAD + q * 4];
        p0[0] = a0x; p0[1] = a0y; p0[2] = a0z; p0[3] = a0w;
        float* p1 = &accum[b1 * APAD + q * 4];
        p1[0] = a1x; p1[1] = a1y; p1[2] = a1z; p1[3] = a1w;
        float* p2 = &accum[b2 * APAD + q * 4];
        p2[0] = a2x; p2[1] = a2y; p2[2] = a2z; p2[3] = a2w;
        float* p3 = &accum[b3 * APAD + q * 4];
        p3[0] = a3x; p3[1] = a3y; p3[2] = a3z; p3[3] = a3w;
    }
    __syncthreads();

    // Stage 2.5: in-place mean-scale + bf16 pack (row floats[0..64) ->
    // packed bf16 pairs in dwords [0..32) of the same row).
    {
        const int bb = tid >> 2;       // 0..127
        const int qq = tid & 3;        // 16-col quarter
        float sc = 1.0f / fmaxf((float)bh[bb], 1.0f);
        float4 f0 = *(const float4*)(accum + bb * APAD + qq * 16 + 0);
        float4 f1 = *(const float4*)(accum + bb * APAD + qq * 16 + 4);
        float4 f2 = *(const float4*)(accum + bb * APAD + qq * 16 + 8);
        float4 f3 = *(const float4*)(accum + bb * APAD + qq * 16 + 12);
        __syncthreads();               // all reads done before overwrite
        uint4 o0, o1;
        o0.x = pk2(f0.x * sc, f0.y * sc); o0.y = pk2(f0.z * sc, f0.w * sc);
        o0.z = pk2(f1.x * sc, f1.y * sc); o0.w = pk2(f1.z * sc, f1.w * sc);
        o1.x = pk2(f2.x * sc, f2.y * sc); o1.y = pk2(f2.z * sc, f2.w * sc);
        o1.z = pk2(f3.x * sc, f3.y * sc); o1.w = pk2(f3.z * sc, f3.w * sc);
        *(uint4*)(accum + bb * APAD + qq * 8 + 0) = o0;
        *(uint4*)(accum + bb * APAD + qq * 8 + 4) = o1;
    }
    __syncthreads();

    // Stage 3: MFMA. A: m=lane&15 (node), k=g*8+j (+32*ks); B from wpk.
    // C/D: col=lane&15, row=(lane>>4)*4+i.
    const int ncol = lane & 15;
    const int g = lane >> 4;
    const int h = wv >> 2;            // relation half
    const int slice = wv & 3;         // output col slice (16 cols)
    f32x4 acc = {0.0f, 0.0f, 0.0f, 0.0f};

#pragma unroll
    for (int rr = 0; rr < 4; ++rr) {
        const int r = h * 4 + rr;
        const int bb = r * TS + ncol;
#pragma unroll
        for (int ks = 0; ks < 2; ++ks) {
            uint4 a4 = *(const uint4*)(accum + bb * APAD + ks * 16 + g * 4);
            uint4 b4 = wpk[((r * 2 + ks) * 4 + g) * 64 + slice * 16 + ncol];
            bf16x8 af = __builtin_bit_cast(bf16x8, a4);
            bf16x8 bf = __builtin_bit_cast(bf16x8, b4);
            acc = __builtin_amdgcn_mfma_f32_16x16x32_bf16(af, bf, acc, 0, 0, 0);
        }
    }
    if (h == 0) {  // root transform from f32 x
        const float* xr = x + ((size_t)tile * TS + ncol) * D + g * 8;
#pragma unroll
        for (int ks = 0; ks < 2; ++ks) {
            float4 lo = *(const float4*)(xr + ks * 32);
            float4 hi = *(const float4*)(xr + ks * 32 + 4);
            bf16x8 af;
            af[0] = f2bf(lo.x); af[1] = f2bf(lo.y);
            af[2] = f2bf(lo.z); af[3] = f2bf(lo.w);
            af[4] = f2bf(hi.x); af[5] = f2bf(hi.y);
            af[6] = f2bf(hi.z); af[7] = f2bf(hi.w);
            uint4 b4 = wpk[NWPK + (ks * 4 + g) * 64 + slice * 16 + ncol];
            bf16x8 bf = __builtin_bit_cast(bf16x8, b4);
            acc = __builtin_amdgcn_mfma_f32_16x16x32_bf16(af, bf, acc, 0, 0, 0);
        }
    }
    __syncthreads();                   // all accum reads done
    float* red = accum;                // alias reuse for cross-half reduction
    const int rrow = g * 4;
    if (h == 1) {
#pragma unroll
        for (int i = 0; i < 4; ++i)
            red[(slice * 16 + rrow + i) * RPAD + ncol] = acc[i];
    }
    __syncthreads();
    if (h == 0) {
        const float bv = bias[slice * 16 + ncol];
#pragma unroll
        for (int i = 0; i < 4; ++i) {
            float v = acc[i] + red[(slice * 16 + rrow + i) * RPAD + ncol] + bv;
            v = fmaxf(v, 0.0f);
            out[((size_t)tile * TS + rrow + i) * D + slice * 16 + ncol] = v;
        }
    }
}

extern "C" void kernel_launch(void* const* d_in, const int* in_sizes, int n_in,
                              void* d_out, int out_size, void* d_ws, size_t ws_size,
                              hipStream_t stream) {
    const float* x    = (const float*)d_in[0];
    const int*   ei   = (const int*)d_in[1];   // [2, NE]
    const int*   et   = (const int*)d_in[2];   // [NE]
    const float* W    = (const float*)d_in[3]; // [NR, D, D]
    const float* Wr   = (const float*)d_in[4]; // [D, D]
    const float* bias = (const float*)d_in[5]; // [D]
    float* out = (float*)d_out;                // [NN, D]

    // ws layout (ints, 16B-aligned blocks):
    // cursor[NT*SUBN*16] | sorted[NT*CAP] | xb[NN*32] | wpk[(NWPK+NWPKR)*uint4]
    int* cursor = (int*)d_ws;
    size_t o1 = (size_t)NT * SUBN * CSTRIDE;
    int* sorted = cursor + o1;
    size_t o2 = o1 + (size_t)NT * CAP;
    unsigned* xb = (unsigned*)(cursor + o2);
    size_t o3 = o2 + (size_t)NN * (D / 2);
    o3 = (o3 + 3) & ~(size_t)3;
    uint4* wpk = (uint4*)(cursor + o3);

    init_kernel<<<(NT * SUBN + 255) / 256, 256, 0, stream>>>(cursor);
    mega_kernel<<<SCB + XPB + PPB, 256, 0, stream>>>(ei, et, x, W, Wr,
                                                     cursor, sorted, xb, wpk);
    fused_kernel<<<NT, 512, 0, stream>>>(x, xb, sorted, cursor, wpk, bias, out);
}

// Round 16
// 179.399 us; speedup vs baseline: 1.0174x; 1.0174x over previous
//
#include <hip/hip_runtime.h>

#define NN 100000
#define NE 1600000
#define D 64
#define NR 8
#define TS 16                  // dst-tile size (nodes per block)
#define NT (NN / TS)           // 6250 tiles, exact
#define APAD 68                // accum row pad (floats)
#define RPAD 17                // reduction scratch pad
#define NB 128                 // (r, dst&15) bins per tile
#define CAP 512                // slots per tile segment
#define CSTRIDE 16             // cursor padding: 1 cursor per 64B line
#define SCHUNK 4096            // edges per scatter block (16/thread)
#define NCH ((NE + SCHUNK - 1) / SCHUNK)   // 391
#define TPS ((NT + 7) / 8)     // tiles per slice: 782
#define NWPK 4096              // W bf16-frag entries (8r x 2ks x 4g x 64col)
#define NWPKR 512              // Wr entries (2ks x 4g x 64col)
#define XPB 12500              // xpack blocks (NN*D/2 / 256)
#define PPB 18                 // prepack blocks
#define SCB (NCH * 8)          // scatter blocks: 3128

typedef short bf16x8 __attribute__((ext_vector_type(8)));
typedef float f32x4 __attribute__((ext_vector_type(4)));

// f32 -> bf16 round-to-nearest-even (finite inputs only)
__device__ __forceinline__ unsigned f2bfu(float f) {
    unsigned u = __float_as_uint(f);
    return (u + 0x7fffu + ((u >> 16) & 1u)) >> 16;
}
__device__ __forceinline__ short f2bf(float f) { return (short)f2bfu(f); }
__device__ __forceinline__ unsigned pk2(float a, float b) {
    return (f2bfu(a) & 0xffffu) | (f2bfu(b) << 16);
}

__global__ void init_kernel(int* __restrict__ cursor) {
    int t = blockIdx.x * blockDim.x + threadIdx.x;
    if (t < NT) cursor[(size_t)t * CSTRIDE] = t * CAP;
}

// Mega kernel: [0,SCB) sliced scatter | [SCB,+XPB) xpack | [+PPB) prepack.
// Scatter: slice = blockIdx&7 (XCD-pinned cursor lines + write window),
// 16 edges/thread phased {d-loads | s,r loads | atomics | stores} so kept
// atomics (mean 2/thread) issue back-to-back.
__global__ void __launch_bounds__(256) mega_kernel(
    const int* __restrict__ ei, const int* __restrict__ et,
    const float* __restrict__ x, const float* __restrict__ W,
    const float* __restrict__ Wr, int* __restrict__ cursor,
    int* __restrict__ sorted, unsigned* __restrict__ xb,
    uint4* __restrict__ wpk)
{
    const int b = blockIdx.x;
    const int tid = threadIdx.x;
    if (b < SCB) {
        const int s8 = b & 7;
        const int c0 = (b >> 3) * SCHUNK;
        const int tlo = s8 * TPS;
        const int thi = min(tlo + TPS, NT);
        int d_[16], t_[16];
        bool keep[16];
#pragma unroll
        for (int k = 0; k < 16; ++k) {
            int e = c0 + tid + k * 256;
            d_[k] = (e < NE) ? ei[NE + e] : -1;
            t_[k] = d_[k] >> 4;
            keep[k] = (d_[k] >= 0) && (t_[k] >= tlo) && (t_[k] < thi);
        }
        int s_[16], r_[16];
#pragma unroll
        for (int k = 0; k < 16; ++k) {
            int e = c0 + tid + k * 256;
            s_[k] = keep[k] ? ei[e] : 0;
            r_[k] = keep[k] ? et[e] : 0;
        }
        int pos[16];
#pragma unroll
        for (int k = 0; k < 16; ++k)
            if (keep[k]) pos[k] = atomicAdd(&cursor[(size_t)t_[k] * CSTRIDE], 1);
#pragma unroll
        for (int k = 0; k < 16; ++k)
            if (keep[k] && pos[k] < t_[k] * CAP + CAP)
                sorted[pos[k]] = s_[k] | (r_[k] << 17) | ((d_[k] & 15) << 20);
    } else if (b < SCB + XPB) {
        int i = (b - SCB) * 256 + tid;          // < NN*D/2 exactly
        float2 f = ((const float2*)x)[i];
        xb[i] = pk2(f.x, f.y);
    } else {
        int e = (b - SCB - XPB) * 256 + tid;
        if (e >= NWPK + NWPKR) return;
        const float* src;
        int col, row0;
        if (e < NWPK) {
            int r = e >> 9, ks = (e >> 8) & 1, g = (e >> 6) & 3;
            col = e & 63;
            src = W + (size_t)r * D * D;
            row0 = ks * 32 + g * 8;
        } else {
            int e2 = e - NWPK;
            int ks = (e2 >> 8) & 1, g = (e2 >> 6) & 3;
            col = e2 & 63;
            src = Wr;
            row0 = ks * 32 + g * 8;
        }
        float v[8];
#pragma unroll
        for (int j = 0; j < 8; ++j) v[j] = src[(size_t)(row0 + j) * D + col];
        uint4 o;
        o.x = pk2(v[0], v[1]); o.y = pk2(v[2], v[3]);
        o.z = pk2(v[4], v[5]); o.w = pk2(v[6], v[7]);
        wpk[e] = o;
    }
}

// One block (8 waves, 512 thr) per dst-tile. Single-pass (csz<=512):
// Stage 1: in-LDS counting sort by bin=(r*16+t), wave-0 shfl prefix scan.
// Stage 2: 16-lane groups serially walk 4 owned bins (2-deep unrolled),
//          f32 register accumulate, single pure-write LDS flush per bin.
// Stage 2.5: in-place mean-scale + f32->bf16 pack (count from bh).
// Stage 3: MFMA (1 ds_read + 1 vmem per MFMA); halves reduced via LDS.
__global__ void __launch_bounds__(512) fused_kernel(
    const float* __restrict__ x, const unsigned* __restrict__ xb,
    const int* __restrict__ sorted, const int* __restrict__ cursor,
    const uint4* __restrict__ wpk, const float* __restrict__ bias,
    float* __restrict__ out)
{
    __shared__ float accum[NR * TS * APAD];   // rows indexed by bin=r*16+t
    __shared__ int eseq[CAP];
    __shared__ int bh[NB], bst[NB], bcur[NB];
    const int tid = threadIdx.x;
    const int lane = tid & 63;
    const int wv = tid >> 6;          // 0..7
    const int grp = tid >> 4;         // 0..31
    const int q = tid & 15;           // 8B slot in row
    const int tile = blockIdx.x;

    int csz = cursor[(size_t)tile * CSTRIDE] - tile * CAP;  // issued early
    if (tid < NB) bh[tid] = 0;
    __syncthreads();

    if (csz > CAP) csz = CAP;
    int rec = 0, bin = 0;
    const bool have = tid < csz;
    if (have) {
        rec = sorted[tile * CAP + tid];
        bin = ((rec >> 17) & 7) * 16 + ((rec >> 20) & 15);
        atomicAdd(&bh[bin], 1);
    }
    __syncthreads();
    if (wv == 0) {                     // parallel 128-bin exclusive scan
        int b0 = bh[2 * lane], b1 = bh[2 * lane + 1];
        int s = b0 + b1;
        int inc = s;
#pragma unroll
        for (int off = 1; off < 64; off <<= 1) {
            int u = __shfl_up(inc, off);
            if (lane >= off) inc += u;
        }
        int excl = inc - s;
        bst[2 * lane] = excl;          bcur[2 * lane] = excl;
        bst[2 * lane + 1] = excl + b0; bcur[2 * lane + 1] = excl + b0;
    }
    __syncthreads();
    if (have) {
        int p = atomicAdd(&bcur[bin], 1);
        eseq[p] = rec;
    }
    __syncthreads();
    for (int bb = grp; bb < NB; bb += 32) {
        int m = bh[bb];
        int st = bst[bb];
        float ax = 0.f, ay = 0.f, az = 0.f, aw = 0.f;
        int i = 0;
        for (; i + 1 < m; i += 2) {
            int s0 = eseq[st + i] & 0x1FFFF;
            int s1 = eseq[st + i + 1] & 0x1FFFF;
            uint2 v0 = *(const uint2*)(xb + (size_t)s0 * (D / 2) + q * 2);
            uint2 v1 = *(const uint2*)(xb + (size_t)s1 * (D / 2) + q * 2);
            ax += __uint_as_float(v0.x << 16) + __uint_as_float(v1.x << 16);
            ay += __uint_as_float(v0.x & 0xffff0000u) + __uint_as_float(v1.x & 0xffff0000u);
            az += __uint_as_float(v0.y << 16) + __uint_as_float(v1.y << 16);
            aw += __uint_as_float(v0.y & 0xffff0000u) + __uint_as_float(v1.y & 0xffff0000u);
        }
        if (i < m) {
            int s0 = eseq[st + i] & 0x1FFFF;
            uint2 v0 = *(const uint2*)(xb + (size_t)s0 * (D / 2) + q * 2);
            ax += __uint_as_float(v0.x << 16);
            ay += __uint_as_float(v0.x & 0xffff0000u);
            az += __uint_as_float(v0.y << 16);
            aw += __uint_as_float(v0.y & 0xffff0000u);
        }
        float* ap = &accum[bb * APAD + q * 4];   // group-owned: pure write
        ap[0] = ax; ap[1] = ay; ap[2] = az; ap[3] = aw;
    }
    __syncthreads();

    // Stage 2.5: in-place mean-scale + bf16 pack (row floats[0..64) ->
    // packed bf16 pairs in dwords [0..32) of the same row).
    {
        const int bb = tid >> 2;       // 0..127
        const int qq = tid & 3;        // 16-col quarter
        float sc = 1.0f / fmaxf((float)bh[bb], 1.0f);
        float4 f0 = *(const float4*)(accum + bb * APAD + qq * 16 + 0);
        float4 f1 = *(const float4*)(accum + bb * APAD + qq * 16 + 4);
        float4 f2 = *(const float4*)(accum + bb * APAD + qq * 16 + 8);
        float4 f3 = *(const float4*)(accum + bb * APAD + qq * 16 + 12);
        __syncthreads();               // all reads done before overwrite
        uint4 o0, o1;
        o0.x = pk2(f0.x * sc, f0.y * sc); o0.y = pk2(f0.z * sc, f0.w * sc);
        o0.z = pk2(f1.x * sc, f1.y * sc); o0.w = pk2(f1.z * sc, f1.w * sc);
        o1.x = pk2(f2.x * sc, f2.y * sc); o1.y = pk2(f2.z * sc, f2.w * sc);
        o1.z = pk2(f3.x * sc, f3.y * sc); o1.w = pk2(f3.z * sc, f3.w * sc);
        *(uint4*)(accum + bb * APAD + qq * 8 + 0) = o0;
        *(uint4*)(accum + bb * APAD + qq * 8 + 4) = o1;
    }
    __syncthreads();

    // Stage 3: MFMA. A: m=lane&15 (node), k=g*8+j (+32*ks); B from wpk.
    // C/D: col=lane&15, row=(lane>>4)*4+i.
    const int ncol = lane & 15;
    const int g = lane >> 4;
    const int h = wv >> 2;            // relation half
    const int slice = wv & 3;         // output col slice (16 cols)
    f32x4 acc = {0.0f, 0.0f, 0.0f, 0.0f};

#pragma unroll
    for (int rr = 0; rr < 4; ++rr) {
        const int r = h * 4 + rr;
        const int bb = r * TS + ncol;
#pragma unroll
        for (int ks = 0; ks < 2; ++ks) {
            uint4 a4 = *(const uint4*)(accum + bb * APAD + ks * 16 + g * 4);
            uint4 b4 = wpk[((r * 2 + ks) * 4 + g) * 64 + slice * 16 + ncol];
            bf16x8 af = __builtin_bit_cast(bf16x8, a4);
            bf16x8 bf = __builtin_bit_cast(bf16x8, b4);
            acc = __builtin_amdgcn_mfma_f32_16x16x32_bf16(af, bf, acc, 0, 0, 0);
        }
    }
    if (h == 0) {  // root transform from f32 x
        const float* xr = x + ((size_t)tile * TS + ncol) * D + g * 8;
#pragma unroll
        for (int ks = 0; ks < 2; ++ks) {
            float4 lo = *(const float4*)(xr + ks * 32);
            float4 hi = *(const float4*)(xr + ks * 32 + 4);
            bf16x8 af;
            af[0] = f2bf(lo.x); af[1] = f2bf(lo.y);
            af[2] = f2bf(lo.z); af[3] = f2bf(lo.w);
            af[4] = f2bf(hi.x); af[5] = f2bf(hi.y);
            af[6] = f2bf(hi.z); af[7] = f2bf(hi.w);
            uint4 b4 = wpk[NWPK + (ks * 4 + g) * 64 + slice * 16 + ncol];
            bf16x8 bf = __builtin_bit_cast(bf16x8, b4);
            acc = __builtin_amdgcn_mfma_f32_16x16x32_bf16(af, bf, acc, 0, 0, 0);
        }
    }
    __syncthreads();                   // all accum reads done
    float* red = accum;                // alias reuse for cross-half reduction
    const int rrow = g * 4;
    if (h == 1) {
#pragma unroll
        for (int i = 0; i < 4; ++i)
            red[(slice * 16 + rrow + i) * RPAD + ncol] = acc[i];
    }
    __syncthreads();
    if (h == 0) {
        const float bv = bias[slice * 16 + ncol];
#pragma unroll
        for (int i = 0; i < 4; ++i) {
            float v = acc[i] + red[(slice * 16 + rrow + i) * RPAD + ncol] + bv;
            v = fmaxf(v, 0.0f);
            out[((size_t)tile * TS + rrow + i) * D + slice * 16 + ncol] = v;
        }
    }
}

extern "C" void kernel_launch(void* const* d_in, const int* in_sizes, int n_in,
                              void* d_out, int out_size, void* d_ws, size_t ws_size,
                              hipStream_t stream) {
    const float* x    = (const float*)d_in[0];
    const int*   ei   = (const int*)d_in[1];   // [2, NE]
    const int*   et   = (const int*)d_in[2];   // [NE]
    const float* W    = (const float*)d_in[3]; // [NR, D, D]
    const float* Wr   = (const float*)d_in[4]; // [D, D]
    const float* bias = (const float*)d_in[5]; // [D]
    float* out = (float*)d_out;                // [NN, D]

    // ws layout (ints, 16B-aligned blocks):
    // cursor[NT*16] | sorted[NT*CAP] | xb[NN*32] | wpk[(NWPK+NWPKR)*uint4]
    int* cursor = (int*)d_ws;
    size_t o1 = (size_t)NT * CSTRIDE;
    int* sorted = cursor + o1;
    size_t o2 = o1 + (size_t)NT * CAP;
    unsigned* xb = (unsigned*)(cursor + o2);
    size_t o3 = o2 + (size_t)NN * (D / 2);
    o3 = (o3 + 3) & ~(size_t)3;
    uint4* wpk = (uint4*)(cursor + o3);

    init_kernel<<<(NT + 255) / 256, 256, 0, stream>>>(cursor);
    mega_kernel<<<SCB + XPB + PPB, 256, 0, stream>>>(ei, et, x, W, Wr,
                                                     cursor, sorted, xb, wpk);
    fused_kernel<<<NT, 512, 0, stream>>>(x, xb, sorted, cursor, wpk, bias, out);
}

// Round 17
// 169.042 us; speedup vs baseline: 1.0797x; 1.0613x over previous
//
#include <hip/hip_runtime.h>

#define NN 100000
#define NE 1600000
#define D 64
#define NR 8
#define TS 16                  // dst-tile size (nodes per block)
#define NT (NN / TS)           // 6250 tiles, exact
#define APAD 68                // accum row pad (floats)
#define RPAD 17                // reduction scratch pad
#define NB 128                 // (r, dst&15) bins per tile
#define CAP 512                // slots per tile segment
#define CSTRIDE 16             // cursor padding: 1 cursor per 64B line
#define SCHUNK 2048            // edges per scatter block (8/thread)
#define NCH ((NE + SCHUNK - 1) / SCHUNK)   // 782
#define TPS ((NT + 7) / 8)     // tiles per slice: 782
#define NWPK 4096              // W bf16-frag entries (8r x 2ks x 4g x 64col)
#define NWPKR 512              // Wr entries (2ks x 4g x 64col)
#define XPB 12500              // xpack blocks (NN*D/2 / 256)
#define PPB 18                 // prepack blocks

typedef short bf16x8 __attribute__((ext_vector_type(8)));
typedef float f32x4 __attribute__((ext_vector_type(4)));

// f32 -> bf16 round-to-nearest-even (finite inputs only)
__device__ __forceinline__ unsigned f2bfu(float f) {
    unsigned u = __float_as_uint(f);
    return (u + 0x7fffu + ((u >> 16) & 1u)) >> 16;
}
__device__ __forceinline__ short f2bf(float f) { return (short)f2bfu(f); }
__device__ __forceinline__ unsigned pk2(float a, float b) {
    return (f2bfu(a) & 0xffffu) | (f2bfu(b) << 16);
}

__global__ void init_kernel(int* __restrict__ cursor) {
    int t = blockIdx.x * blockDim.x + threadIdx.x;
    if (t < NT) cursor[(size_t)t * CSTRIDE] = t * CAP;
}

// Setup: xpack (x->bf16) | prepack (W,Wr -> B-frag bf16)
__global__ void __launch_bounds__(256) setup_kernel(
    const float* __restrict__ x, const float* __restrict__ W,
    const float* __restrict__ Wr, unsigned* __restrict__ xb,
    uint4* __restrict__ wpk)
{
    const int b = blockIdx.x;
    const int tid = threadIdx.x;
    if (b < XPB) {
        int i = b * 256 + tid;                 // < NN*D/2 exactly
        float2 f = ((const float2*)x)[i];
        xb[i] = pk2(f.x, f.y);
    } else {
        int e = (b - XPB) * 256 + tid;
        if (e >= NWPK + NWPKR) return;
        const float* src;
        int col, row0;
        if (e < NWPK) {
            int r = e >> 9, ks = (e >> 8) & 1, g = (e >> 6) & 3;
            col = e & 63;
            src = W + (size_t)r * D * D;
            row0 = ks * 32 + g * 8;
        } else {
            int e2 = e - NWPK;
            int ks = (e2 >> 8) & 1, g = (e2 >> 6) & 3;
            col = e2 & 63;
            src = Wr;
            row0 = ks * 32 + g * 8;
        }
        float v[8];
#pragma unroll
        for (int j = 0; j < 8; ++j) v[j] = src[(size_t)(row0 + j) * D + col];
        uint4 o;
        o.x = pk2(v[0], v[1]); o.y = pk2(v[2], v[3]);
        o.z = pk2(v[4], v[5]); o.w = pk2(v[6], v[7]);
        wpk[e] = o;
    }
}

// Sliced lean scatter (R10 structure): slice=blockIdx&7 (XCD-pinned cursor
// lines + write window); d[8] prefetch then minimal serial body. Low VGPR ->
// max waves -> atomic latency hidden by TLP, not ILP.
__global__ void __launch_bounds__(256, 8) scatter_kernel(
    const int* __restrict__ ei, const int* __restrict__ et,
    int* __restrict__ cursor, int* __restrict__ sorted)
{
    const int s8 = blockIdx.x & 7;
    const int c0 = (blockIdx.x >> 3) * SCHUNK;
    const int tlo = s8 * TPS;
    const int thi = min(tlo + TPS, NT);
    int d[8];
#pragma unroll
    for (int k = 0; k < 8; ++k) {
        int e = c0 + threadIdx.x + k * 256;
        d[k] = (e < NE) ? ei[NE + e] : -1;
    }
#pragma unroll
    for (int k = 0; k < 8; ++k) {
        int t = d[k] >> 4;                 // -1 -> negative, fails test
        if (d[k] < 0 || t < tlo || t >= thi) continue;
        int e = c0 + threadIdx.x + k * 256;
        int src = ei[e];
        int r = et[e];
        int pos = atomicAdd(&cursor[(size_t)t * CSTRIDE], 1);
        if (pos < t * CAP + CAP)
            sorted[pos] = src | (r << 17) | ((d[k] & 15) << 20);
    }
}

// One block (8 waves, 512 thr) per dst-tile. Single-pass (csz<=512):
// Stage 1: in-LDS counting sort by bin=(r*16+t), wave-0 shfl prefix scan.
// Stage 2: 16-lane groups serially walk 4 owned bins (2-deep unrolled),
//          f32 register accumulate, single pure-write LDS flush per bin.
// Stage 2.5: in-place mean-scale + f32->bf16 pack (count from bh).
// Stage 3: MFMA (1 ds_read + 1 vmem per MFMA); halves reduced via LDS.
__global__ void __launch_bounds__(512) fused_kernel(
    const float* __restrict__ x, const unsigned* __restrict__ xb,
    const int* __restrict__ sorted, const int* __restrict__ cursor,
    const uint4* __restrict__ wpk, const float* __restrict__ bias,
    float* __restrict__ out)
{
    __shared__ float accum[NR * TS * APAD];   // rows indexed by bin=r*16+t
    __shared__ int eseq[CAP];
    __shared__ int bh[NB], bst[NB], bcur[NB];
    const int tid = threadIdx.x;
    const int lane = tid & 63;
    const int wv = tid >> 6;          // 0..7
    const int grp = tid >> 4;         // 0..31
    const int q = tid & 15;           // 8B slot in row
    const int tile = blockIdx.x;

    int csz = cursor[(size_t)tile * CSTRIDE] - tile * CAP;  // issued early
    if (tid < NB) bh[tid] = 0;
    __syncthreads();

    if (csz > CAP) csz = CAP;
    int rec = 0, bin = 0;
    const bool have = tid < csz;
    if (have) {
        rec = sorted[tile * CAP + tid];
        bin = ((rec >> 17) & 7) * 16 + ((rec >> 20) & 15);
        atomicAdd(&bh[bin], 1);
    }
    __syncthreads();
    if (wv == 0) {                     // parallel 128-bin exclusive scan
        int b0 = bh[2 * lane], b1 = bh[2 * lane + 1];
        int s = b0 + b1;
        int inc = s;
#pragma unroll
        for (int off = 1; off < 64; off <<= 1) {
            int u = __shfl_up(inc, off);
            if (lane >= off) inc += u;
        }
        int excl = inc - s;
        bst[2 * lane] = excl;          bcur[2 * lane] = excl;
        bst[2 * lane + 1] = excl + b0; bcur[2 * lane + 1] = excl + b0;
    }
    __syncthreads();
    if (have) {
        int p = atomicAdd(&bcur[bin], 1);
        eseq[p] = rec;
    }
    __syncthreads();
    for (int bb = grp; bb < NB; bb += 32) {
        int m = bh[bb];
        int st = bst[bb];
        float ax = 0.f, ay = 0.f, az = 0.f, aw = 0.f;
        int i = 0;
        for (; i + 1 < m; i += 2) {
            int s0 = eseq[st + i] & 0x1FFFF;
            int s1 = eseq[st + i + 1] & 0x1FFFF;
            uint2 v0 = *(const uint2*)(xb + (size_t)s0 * (D / 2) + q * 2);
            uint2 v1 = *(const uint2*)(xb + (size_t)s1 * (D / 2) + q * 2);
            ax += __uint_as_float(v0.x << 16) + __uint_as_float(v1.x << 16);
            ay += __uint_as_float(v0.x & 0xffff0000u) + __uint_as_float(v1.x & 0xffff0000u);
            az += __uint_as_float(v0.y << 16) + __uint_as_float(v1.y << 16);
            aw += __uint_as_float(v0.y & 0xffff0000u) + __uint_as_float(v1.y & 0xffff0000u);
        }
        if (i < m) {
            int s0 = eseq[st + i] & 0x1FFFF;
            uint2 v0 = *(const uint2*)(xb + (size_t)s0 * (D / 2) + q * 2);
            ax += __uint_as_float(v0.x << 16);
            ay += __uint_as_float(v0.x & 0xffff0000u);
            az += __uint_as_float(v0.y << 16);
            aw += __uint_as_float(v0.y & 0xffff0000u);
        }
        float* ap = &accum[bb * APAD + q * 4];   // group-owned: pure write
        ap[0] = ax; ap[1] = ay; ap[2] = az; ap[3] = aw;
    }
    __syncthreads();

    // Stage 2.5: in-place mean-scale + bf16 pack (row floats[0..64) ->
    // packed bf16 pairs in dwords [0..32) of the same row).
    {
        const int bb = tid >> 2;       // 0..127
        const int qq = tid & 3;        // 16-col quarter
        float sc = 1.0f / fmaxf((float)bh[bb], 1.0f);
        float4 f0 = *(const float4*)(accum + bb * APAD + qq * 16 + 0);
        float4 f1 = *(const float4*)(accum + bb * APAD + qq * 16 + 4);
        float4 f2 = *(const float4*)(accum + bb * APAD + qq * 16 + 8);
        float4 f3 = *(const float4*)(accum + bb * APAD + qq * 16 + 12);
        __syncthreads();               // all reads done before overwrite
        uint4 o0, o1;
        o0.x = pk2(f0.x * sc, f0.y * sc); o0.y = pk2(f0.z * sc, f0.w * sc);
        o0.z = pk2(f1.x * sc, f1.y * sc); o0.w = pk2(f1.z * sc, f1.w * sc);
        o1.x = pk2(f2.x * sc, f2.y * sc); o1.y = pk2(f2.z * sc, f2.w * sc);
        o1.z = pk2(f3.x * sc, f3.y * sc); o1.w = pk2(f3.z * sc, f3.w * sc);
        *(uint4*)(accum + bb * APAD + qq * 8 + 0) = o0;
        *(uint4*)(accum + bb * APAD + qq * 8 + 4) = o1;
    }
    __syncthreads();

    // Stage 3: MFMA. A: m=lane&15 (node), k=g*8+j (+32*ks); B from wpk.
    // C/D: col=lane&15, row=(lane>>4)*4+i.
    const int ncol = lane & 15;
    const int g = lane >> 4;
    const int h = wv >> 2;            // relation half
    const int slice = wv & 3;         // output col slice (16 cols)
    f32x4 acc = {0.0f, 0.0f, 0.0f, 0.0f};

#pragma unroll
    for (int rr = 0; rr < 4; ++rr) {
        const int r = h * 4 + rr;
        const int bb = r * TS + ncol;
#pragma unroll
        for (int ks = 0; ks < 2; ++ks) {
            uint4 a4 = *(const uint4*)(accum + bb * APAD + ks * 16 + g * 4);
            uint4 b4 = wpk[((r * 2 + ks) * 4 + g) * 64 + slice * 16 + ncol];
            bf16x8 af = __builtin_bit_cast(bf16x8, a4);
            bf16x8 bf = __builtin_bit_cast(bf16x8, b4);
            acc = __builtin_amdgcn_mfma_f32_16x16x32_bf16(af, bf, acc, 0, 0, 0);
        }
    }
    if (h == 0) {  // root transform from f32 x
        const float* xr = x + ((size_t)tile * TS + ncol) * D + g * 8;
#pragma unroll
        for (int ks = 0; ks < 2; ++ks) {
            float4 lo = *(const float4*)(xr + ks * 32);
            float4 hi = *(const float4*)(xr + ks * 32 + 4);
            bf16x8 af;
            af[0] = f2bf(lo.x); af[1] = f2bf(lo.y);
            af[2] = f2bf(lo.z); af[3] = f2bf(lo.w);
            af[4] = f2bf(hi.x); af[5] = f2bf(hi.y);
            af[6] = f2bf(hi.z); af[7] = f2bf(hi.w);
            uint4 b4 = wpk[NWPK + (ks * 4 + g) * 64 + slice * 16 + ncol];
            bf16x8 bf = __builtin_bit_cast(bf16x8, b4);
            acc = __builtin_amdgcn_mfma_f32_16x16x32_bf16(af, bf, acc, 0, 0, 0);
        }
    }
    __syncthreads();                   // all accum reads done
    float* red = accum;                // alias reuse for cross-half reduction
    const int rrow = g * 4;
    if (h == 1) {
#pragma unroll
        for (int i = 0; i < 4; ++i)
            red[(slice * 16 + rrow + i) * RPAD + ncol] = acc[i];
    }
    __syncthreads();
    if (h == 0) {
        const float bv = bias[slice * 16 + ncol];
#pragma unroll
        for (int i = 0; i < 4; ++i) {
            float v = acc[i] + red[(slice * 16 + rrow + i) * RPAD + ncol] + bv;
            v = fmaxf(v, 0.0f);
            out[((size_t)tile * TS + rrow + i) * D + slice * 16 + ncol] = v;
        }
    }
}

extern "C" void kernel_launch(void* const* d_in, const int* in_sizes, int n_in,
                              void* d_out, int out_size, void* d_ws, size_t ws_size,
                              hipStream_t stream) {
    const float* x    = (const float*)d_in[0];
    const int*   ei   = (const int*)d_in[1];   // [2, NE]
    const int*   et   = (const int*)d_in[2];   // [NE]
    const float* W    = (const float*)d_in[3]; // [NR, D, D]
    const float* Wr   = (const float*)d_in[4]; // [D, D]
    const float* bias = (const float*)d_in[5]; // [D]
    float* out = (float*)d_out;                // [NN, D]

    // ws layout (ints, 16B-aligned blocks):
    // cursor[NT*16] | sorted[NT*CAP] | xb[NN*32] | wpk[(NWPK+NWPKR)*uint4]
    int* cursor = (int*)d_ws;
    size_t o1 = (size_t)NT * CSTRIDE;
    int* sorted = cursor + o1;
    size_t o2 = o1 + (size_t)NT * CAP;
    unsigned* xb = (unsigned*)(cursor + o2);
    size_t o3 = o2 + (size_t)NN * (D / 2);
    o3 = (o3 + 3) & ~(size_t)3;
    uint4* wpk = (uint4*)(cursor + o3);

    init_kernel<<<(NT + 255) / 256, 256, 0, stream>>>(cursor);
    setup_kernel<<<XPB + PPB, 256, 0, stream>>>(x, W, Wr, xb, wpk);
    scatter_kernel<<<NCH * 8, 256, 0, stream>>>(ei, et, cursor, sorted);
    fused_kernel<<<NT, 512, 0, stream>>>(x, xb, sorted, cursor, wpk, bias, out);
}

// Round 18
// 162.598 us; speedup vs baseline: 1.1225x; 1.0396x over previous
//
#include <hip/hip_runtime.h>

#define NN 100000
#define NE 1600000
#define D 64
#define NR 8
#define TS 16                  // dst-tile size (nodes per block)
#define NT (NN / TS)           // 6250 tiles, exact
#define APK 36                 // packed accum row stride (dwords): 32 data + 4 pad
#define RPAD 17                // reduction scratch pad (floats)
#define NB 128                 // (r, dst&15) bins per tile
#define CAP 512                // slots per tile segment
#define CSTRIDE 16             // cursor padding: 1 cursor per 64B line
#define SCHUNK 2048            // edges per scatter block (8/thread)
#define NCH ((NE + SCHUNK - 1) / SCHUNK)   // 782
#define TPS ((NT + 7) / 8)     // tiles per slice: 782
#define NWPK 4096              // W bf16-frag entries (8r x 2ks x 4g x 64col)
#define NWPKR 512              // Wr entries (2ks x 4g x 64col)
#define XPB 12500              // xpack blocks (NN*D/2 / 256)
#define PPB 18                 // prepack blocks

typedef short bf16x8 __attribute__((ext_vector_type(8)));
typedef float f32x4 __attribute__((ext_vector_type(4)));

// f32 -> bf16 round-to-nearest-even (finite inputs only)
__device__ __forceinline__ unsigned f2bfu(float f) {
    unsigned u = __float_as_uint(f);
    return (u + 0x7fffu + ((u >> 16) & 1u)) >> 16;
}
__device__ __forceinline__ unsigned pk2(float a, float b) {
    return (f2bfu(a) & 0xffffu) | (f2bfu(b) << 16);
}

__global__ void init_kernel(int* __restrict__ cursor) {
    int t = blockIdx.x * blockDim.x + threadIdx.x;
    if (t < NT) cursor[(size_t)t * CSTRIDE] = t * CAP;
}

// Setup: xpack (x->bf16 packed rows) | prepack (W,Wr -> B-frag bf16)
__global__ void __launch_bounds__(256) setup_kernel(
    const float* __restrict__ x, const float* __restrict__ W,
    const float* __restrict__ Wr, unsigned* __restrict__ xb,
    uint4* __restrict__ wpk)
{
    const int b = blockIdx.x;
    const int tid = threadIdx.x;
    if (b < XPB) {
        int i = b * 256 + tid;                 // < NN*D/2 exactly
        float2 f = ((const float2*)x)[i];
        xb[i] = pk2(f.x, f.y);
    } else {
        int e = (b - XPB) * 256 + tid;
        if (e >= NWPK + NWPKR) return;
        const float* src;
        int col, row0;
        if (e < NWPK) {
            int r = e >> 9, ks = (e >> 8) & 1, g = (e >> 6) & 3;
            col = e & 63;
            src = W + (size_t)r * D * D;
            row0 = ks * 32 + g * 8;
        } else {
            int e2 = e - NWPK;
            int ks = (e2 >> 8) & 1, g = (e2 >> 6) & 3;
            col = e2 & 63;
            src = Wr;
            row0 = ks * 32 + g * 8;
        }
        float v[8];
#pragma unroll
        for (int j = 0; j < 8; ++j) v[j] = src[(size_t)(row0 + j) * D + col];
        uint4 o;
        o.x = pk2(v[0], v[1]); o.y = pk2(v[2], v[3]);
        o.z = pk2(v[4], v[5]); o.w = pk2(v[6], v[7]);
        wpk[e] = o;
    }
}

// Sliced lean scatter: slice=blockIdx&7 (XCD-pinned cursor lines + write
// window); d[8] prefetch then minimal serial body. Low VGPR -> max waves.
__global__ void __launch_bounds__(256, 8) scatter_kernel(
    const int* __restrict__ ei, const int* __restrict__ et,
    int* __restrict__ cursor, int* __restrict__ sorted)
{
    const int s8 = blockIdx.x & 7;
    const int c0 = (blockIdx.x >> 3) * SCHUNK;
    const int tlo = s8 * TPS;
    const int thi = min(tlo + TPS, NT);
    int d[8];
#pragma unroll
    for (int k = 0; k < 8; ++k) {
        int e = c0 + threadIdx.x + k * 256;
        d[k] = (e < NE) ? ei[NE + e] : -1;
    }
#pragma unroll
    for (int k = 0; k < 8; ++k) {
        int t = d[k] >> 4;                 // -1 -> negative, fails test
        if (d[k] < 0 || t < tlo || t >= thi) continue;
        int e = c0 + threadIdx.x + k * 256;
        int src = ei[e];
        int r = et[e];
        int pos = atomicAdd(&cursor[(size_t)t * CSTRIDE], 1);
        if (pos < t * CAP + CAP)
            sorted[pos] = src | (r << 17) | ((d[k] & 15) << 20);
    }
}

// One block (8 waves, 512 thr) per dst-tile. Single-pass (csz<=512):
// Stage 1: in-LDS counting sort by bin=(r*16+t), wave-0 shfl prefix scan.
// Stage 2: 16-lane groups serially walk 4 owned bins (2-deep unrolled),
//          f32 register accumulate; flush = mean-scale + bf16-pack + single
//          packed LDS write (stage 2.5 eliminated).
// Stage 3: MFMA (A from packed LDS rows, B from wpk, root A from xb);
//          halves reduced via LDS.
__global__ void __launch_bounds__(512) fused_kernel(
    const unsigned* __restrict__ xb, const int* __restrict__ sorted,
    const int* __restrict__ cursor, const uint4* __restrict__ wpk,
    const float* __restrict__ bias, float* __restrict__ out)
{
    __shared__ unsigned accum[NB * APK];   // packed bf16 rows, bin=r*16+t
    __shared__ int eseq[CAP];
    __shared__ int bh[NB], bst[NB], bcur[NB];
    const int tid = threadIdx.x;
    const int lane = tid & 63;
    const int wv = tid >> 6;          // 0..7
    const int grp = tid >> 4;         // 0..31
    const int q = tid & 15;           // 8B slot in row
    const int tile = blockIdx.x;

    int csz = cursor[(size_t)tile * CSTRIDE] - tile * CAP;  // issued early
    if (tid < NB) bh[tid] = 0;
    __syncthreads();

    if (csz > CAP) csz = CAP;
    int rec = 0, bin = 0;
    const bool have = tid < csz;
    if (have) {
        rec = sorted[tile * CAP + tid];
        bin = ((rec >> 17) & 7) * 16 + ((rec >> 20) & 15);
        atomicAdd(&bh[bin], 1);
    }
    __syncthreads();
    if (wv == 0) {                     // parallel 128-bin exclusive scan
        int b0 = bh[2 * lane], b1 = bh[2 * lane + 1];
        int s = b0 + b1;
        int inc = s;
#pragma unroll
        for (int off = 1; off < 64; off <<= 1) {
            int u = __shfl_up(inc, off);
            if (lane >= off) inc += u;
        }
        int excl = inc - s;
        bst[2 * lane] = excl;          bcur[2 * lane] = excl;
        bst[2 * lane + 1] = excl + b0; bcur[2 * lane + 1] = excl + b0;
    }
    __syncthreads();
    if (have) {
        int p = atomicAdd(&bcur[bin], 1);
        eseq[p] = rec;
    }
    __syncthreads();
    for (int bb = grp; bb < NB; bb += 32) {
        int m = bh[bb];
        int st = bst[bb];
        float ax = 0.f, ay = 0.f, az = 0.f, aw = 0.f;
        int i = 0;
        for (; i + 1 < m; i += 2) {
            int s0 = eseq[st + i] & 0x1FFFF;
            int s1 = eseq[st + i + 1] & 0x1FFFF;
            uint2 v0 = *(const uint2*)(xb + (size_t)s0 * (D / 2) + q * 2);
            uint2 v1 = *(const uint2*)(xb + (size_t)s1 * (D / 2) + q * 2);
            ax += __uint_as_float(v0.x << 16) + __uint_as_float(v1.x << 16);
            ay += __uint_as_float(v0.x & 0xffff0000u) + __uint_as_float(v1.x & 0xffff0000u);
            az += __uint_as_float(v0.y << 16) + __uint_as_float(v1.y << 16);
            aw += __uint_as_float(v0.y & 0xffff0000u) + __uint_as_float(v1.y & 0xffff0000u);
        }
        if (i < m) {
            int s0 = eseq[st + i] & 0x1FFFF;
            uint2 v0 = *(const uint2*)(xb + (size_t)s0 * (D / 2) + q * 2);
            ax += __uint_as_float(v0.x << 16);
            ay += __uint_as_float(v0.x & 0xffff0000u);
            az += __uint_as_float(v0.y << 16);
            aw += __uint_as_float(v0.y & 0xffff0000u);
        }
        float sc = 1.0f / fmaxf((float)m, 1.0f);   // mean fold: scale at flush
        unsigned* ap = &accum[bb * APK + q * 2];   // group-owned: pure write
        ap[0] = pk2(ax * sc, ay * sc);
        ap[1] = pk2(az * sc, aw * sc);
    }
    __syncthreads();

    // Stage 3: MFMA. A: m=lane&15 (node), k=g*8+j (+32*ks); B from wpk.
    // C/D: col=lane&15, row=(lane>>4)*4+i.
    const int ncol = lane & 15;
    const int g = lane >> 4;
    const int h = wv >> 2;            // relation half
    const int slice = wv & 3;         // output col slice (16 cols)
    f32x4 acc = {0.0f, 0.0f, 0.0f, 0.0f};

#pragma unroll
    for (int rr = 0; rr < 4; ++rr) {
        const int r = h * 4 + rr;
        const int bb = r * TS + ncol;
#pragma unroll
        for (int ks = 0; ks < 2; ++ks) {
            uint4 a4 = *(const uint4*)(accum + bb * APK + ks * 16 + g * 4);
            uint4 b4 = wpk[((r * 2 + ks) * 4 + g) * 64 + slice * 16 + ncol];
            bf16x8 af = __builtin_bit_cast(bf16x8, a4);
            bf16x8 bf = __builtin_bit_cast(bf16x8, b4);
            acc = __builtin_amdgcn_mfma_f32_16x16x32_bf16(af, bf, acc, 0, 0, 0);
        }
    }
    if (h == 0) {  // root transform: A-frags straight from packed xb
        const unsigned* xr = xb + (size_t)(tile * TS + ncol) * (D / 2);
#pragma unroll
        for (int ks = 0; ks < 2; ++ks) {
            uint4 a4 = *(const uint4*)(xr + ks * 16 + g * 4);
            bf16x8 af = __builtin_bit_cast(bf16x8, a4);
            uint4 b4 = wpk[NWPK + (ks * 4 + g) * 64 + slice * 16 + ncol];
            bf16x8 bf = __builtin_bit_cast(bf16x8, b4);
            acc = __builtin_amdgcn_mfma_f32_16x16x32_bf16(af, bf, acc, 0, 0, 0);
        }
    }
    __syncthreads();                   // all accum reads done
    float* red = (float*)accum;        // alias reuse for cross-half reduction
    const int rrow = g * 4;
    if (h == 1) {
#pragma unroll
        for (int i = 0; i < 4; ++i)
            red[(slice * 16 + rrow + i) * RPAD + ncol] = acc[i];
    }
    __syncthreads();
    if (h == 0) {
        const float bv = bias[slice * 16 + ncol];
#pragma unroll
        for (int i = 0; i < 4; ++i) {
            float v = acc[i] + red[(slice * 16 + rrow + i) * RPAD + ncol] + bv;
            v = fmaxf(v, 0.0f);
            out[((size_t)tile * TS + rrow + i) * D + slice * 16 + ncol] = v;
        }
    }
}

extern "C" void kernel_launch(void* const* d_in, const int* in_sizes, int n_in,
                              void* d_out, int out_size, void* d_ws, size_t ws_size,
                              hipStream_t stream) {
    const float* x    = (const float*)d_in[0];
    const int*   ei   = (const int*)d_in[1];   // [2, NE]
    const int*   et   = (const int*)d_in[2];   // [NE]
    const float* W    = (const float*)d_in[3]; // [NR, D, D]
    const float* Wr   = (const float*)d_in[4]; // [D, D]
    const float* bias = (const float*)d_in[5]; // [D]
    float* out = (float*)d_out;                // [NN, D]

    // ws layout (ints, 16B-aligned blocks):
    // cursor[NT*16] | sorted[NT*CAP] | xb[NN*32] | wpk[(NWPK+NWPKR)*uint4]
    int* cursor = (int*)d_ws;
    size_t o1 = (size_t)NT * CSTRIDE;
    int* sorted = cursor + o1;
    size_t o2 = o1 + (size_t)NT * CAP;
    unsigned* xb = (unsigned*)(cursor + o2);
    size_t o3 = o2 + (size_t)NN * (D / 2);
    o3 = (o3 + 3) & ~(size_t)3;
    uint4* wpk = (uint4*)(cursor + o3);

    init_kernel<<<(NT + 255) / 256, 256, 0, stream>>>(cursor);
    setup_kernel<<<XPB + PPB, 256, 0, stream>>>(x, W, Wr, xb, wpk);
    scatter_kernel<<<NCH * 8, 256, 0, stream>>>(ei, et, cursor, sorted);
    fused_kernel<<<NT, 512, 0, stream>>>(xb, sorted, cursor, wpk, bias, out);
}

// Round 20
// 152.956 us; speedup vs baseline: 1.1933x; 1.0630x over previous
//
#include <hip/hip_runtime.h>

#define NN 100000
#define NE 1600000
#define D 64
#define NR 8
#define TS 16                  // dst-tile size (nodes per block)
#define NT (NN / TS)           // 6250 tiles, exact
#define APK 36                 // packed accum row stride (dwords): 32 data + 4 pad
#define RPAD 17                // reduction scratch pad (floats)
#define NB 128                 // (r, dst&15) bins per tile
#define CAP 512                // slots per tile segment
#define CSTRIDE 16             // cursor padding: 1 cursor per 64B line
#define SCHUNK 2048            // edges per scatter block (8/thread)
#define NCH ((NE + SCHUNK - 1) / SCHUNK)   // 782
#define TPS ((NT + 7) / 8)     // tiles per slice: 782
#define NWPK 4096              // W bf16-frag entries (8r x 2ks x 4g x 64col)
#define NWPKR 512              // Wr entries (2ks x 4g x 64col)
#define XPB 12500              // xpack blocks (NN*D/2 / 256)
#define PPB 18                 // prepack blocks

typedef short bf16x8 __attribute__((ext_vector_type(8)));
typedef float f32x4 __attribute__((ext_vector_type(4)));

// f32 -> bf16 round-to-nearest-even (finite inputs only)
__device__ __forceinline__ unsigned f2bfu(float f) {
    unsigned u = __float_as_uint(f);
    return (u + 0x7fffu + ((u >> 16) & 1u)) >> 16;
}
__device__ __forceinline__ unsigned pk2(float a, float b) {
    return (f2bfu(a) & 0xffffu) | (f2bfu(b) << 16);
}

__global__ void init_kernel(int* __restrict__ cursor) {
    int t = blockIdx.x * blockDim.x + threadIdx.x;
    if (t < NT) cursor[(size_t)t * CSTRIDE] = t * CAP;
}

// Setup: xpack (x->bf16 packed rows) | prepack (W,Wr -> B-frag bf16)
__global__ void __launch_bounds__(256) setup_kernel(
    const float* __restrict__ x, const float* __restrict__ W,
    const float* __restrict__ Wr, unsigned* __restrict__ xb,
    uint4* __restrict__ wpk)
{
    const int b = blockIdx.x;
    const int tid = threadIdx.x;
    if (b < XPB) {
        int i = b * 256 + tid;                 // < NN*D/2 exactly
        float2 f = ((const float2*)x)[i];
        xb[i] = pk2(f.x, f.y);
    } else {
        int e = (b - XPB) * 256 + tid;
        if (e >= NWPK + NWPKR) return;
        const float* src;
        int col, row0;
        if (e < NWPK) {
            int r = e >> 9, ks = (e >> 8) & 1, g = (e >> 6) & 3;
            col = e & 63;
            src = W + (size_t)r * D * D;
            row0 = ks * 32 + g * 8;
        } else {
            int e2 = e - NWPK;
            int ks = (e2 >> 8) & 1, g = (e2 >> 6) & 3;
            col = e2 & 63;
            src = Wr;
            row0 = ks * 32 + g * 8;
        }
        float v[8];
#pragma unroll
        for (int j = 0; j < 8; ++j) v[j] = src[(size_t)(row0 + j) * D + col];
        uint4 o;
        o.x = pk2(v[0], v[1]); o.y = pk2(v[2], v[3]);
        o.z = pk2(v[4], v[5]); o.w = pk2(v[6], v[7]);
        wpk[e] = o;
    }
}

// Sliced lean scatter: slice=blockIdx&7 (XCD-pinned cursor lines + write
// window); d[8] prefetch then minimal serial body. Low VGPR -> max waves.
__global__ void __launch_bounds__(256, 8) scatter_kernel(
    const int* __restrict__ ei, const int* __restrict__ et,
    int* __restrict__ cursor, int* __restrict__ sorted)
{
    const int s8 = blockIdx.x & 7;
    const int c0 = (blockIdx.x >> 3) * SCHUNK;
    const int tlo = s8 * TPS;
    const int thi = min(tlo + TPS, NT);
    int d[8];
#pragma unroll
    for (int k = 0; k < 8; ++k) {
        int e = c0 + threadIdx.x + k * 256;
        d[k] = (e < NE) ? ei[NE + e] : -1;
    }
#pragma unroll
    for (int k = 0; k < 8; ++k) {
        int t = d[k] >> 4;                 // -1 -> negative, fails test
        if (d[k] < 0 || t < tlo || t >= thi) continue;
        int e = c0 + threadIdx.x + k * 256;
        int src = ei[e];
        int r = et[e];
        int pos = atomicAdd(&cursor[(size_t)t * CSTRIDE], 1);
        if (pos < t * CAP + CAP)
            sorted[pos] = src | (r << 17) | ((d[k] & 15) << 20);
    }
}

// One block (8 waves, 512 thr) per dst-tile. Single-pass (csz<=512):
// Stage 1: in-LDS counting sort by bin=(r*16+t), wave-0 shfl prefix scan.
// Stage 2: 64 groups of 8 lanes; each group owns 2 bins (mean 4 edges) —
//          half the serial gather depth of 16-lane/4-bin. Lane loads uint4
//          (8 dims), f32 register accumulate; flush = mean-scale + bf16 pack.
// Stage 3: MFMA (A from packed LDS rows, B from wpk, root A from xb);
//          halves reduced via LDS.
__global__ void __launch_bounds__(512) fused_kernel(
    const unsigned* __restrict__ xb, const int* __restrict__ sorted,
    const int* __restrict__ cursor, const uint4* __restrict__ wpk,
    const float* __restrict__ bias, float* __restrict__ out)
{
    __shared__ unsigned accum[NB * APK];   // packed bf16 rows, bin=r*16+t
    __shared__ int eseq[CAP];
    __shared__ int bh[NB], bst[NB], bcur[NB];
    const int tid = threadIdx.x;
    const int lane = tid & 63;
    const int wv = tid >> 6;          // 0..7
    const int tile = blockIdx.x;

    int csz = cursor[(size_t)tile * CSTRIDE] - tile * CAP;  // issued early
    if (tid < NB) bh[tid] = 0;
    __syncthreads();

    if (csz > CAP) csz = CAP;
    int rec = 0, bin = 0;
    const bool have = tid < csz;
    if (have) {
        rec = sorted[tile * CAP + tid];
        bin = ((rec >> 17) & 7) * 16 + ((rec >> 20) & 15);
        atomicAdd(&bh[bin], 1);
    }
    __syncthreads();
    if (wv == 0) {                     // parallel 128-bin exclusive scan
        int b0 = bh[2 * lane], b1 = bh[2 * lane + 1];
        int s = b0 + b1;
        int inc = s;
#pragma unroll
        for (int off = 1; off < 64; off <<= 1) {
            int u = __shfl_up(inc, off);
            if (lane >= off) inc += u;
        }
        int excl = inc - s;
        bst[2 * lane] = excl;          bcur[2 * lane] = excl;
        bst[2 * lane + 1] = excl + b0; bcur[2 * lane + 1] = excl + b0;
    }
    __syncthreads();
    if (have) {
        int p = atomicAdd(&bcur[bin], 1);
        eseq[p] = rec;
    }
    __syncthreads();
    {
        const int grp8 = tid >> 3;     // 0..63
        const int q8 = tid & 7;        // uint4 slot in row (8 dims)
#pragma unroll
        for (int half = 0; half < 2; ++half) {
            const int bb = grp8 + half * 64;
            int m = bh[bb];
            int st = bst[bb];
            float a0=0.f,a1=0.f,a2=0.f,a3=0.f,a4=0.f,a5=0.f,a6=0.f,a7=0.f;
            int i = 0;
            for (; i + 1 < m; i += 2) {
                int s0 = eseq[st + i] & 0x1FFFF;
                int s1 = eseq[st + i + 1] & 0x1FFFF;
                uint4 v0 = *(const uint4*)(xb + (size_t)s0 * (D / 2) + q8 * 4);
                uint4 v1 = *(const uint4*)(xb + (size_t)s1 * (D / 2) + q8 * 4);
                a0 += __uint_as_float(v0.x << 16) + __uint_as_float(v1.x << 16);
                a1 += __uint_as_float(v0.x & 0xffff0000u) + __uint_as_float(v1.x & 0xffff0000u);
                a2 += __uint_as_float(v0.y << 16) + __uint_as_float(v1.y << 16);
                a3 += __uint_as_float(v0.y & 0xffff0000u) + __uint_as_float(v1.y & 0xffff0000u);
                a4 += __uint_as_float(v0.z << 16) + __uint_as_float(v1.z << 16);
                a5 += __uint_as_float(v0.z & 0xffff0000u) + __uint_as_float(v1.z & 0xffff0000u);
                a6 += __uint_as_float(v0.w << 16) + __uint_as_float(v1.w << 16);
                a7 += __uint_as_float(v0.w & 0xffff0000u) + __uint_as_float(v1.w & 0xffff0000u);
            }
            if (i < m) {
                int s0 = eseq[st + i] & 0x1FFFF;
                uint4 v0 = *(const uint4*)(xb + (size_t)s0 * (D / 2) + q8 * 4);
                a0 += __uint_as_float(v0.x << 16);
                a1 += __uint_as_float(v0.x & 0xffff0000u);
                a2 += __uint_as_float(v0.y << 16);
                a3 += __uint_as_float(v0.y & 0xffff0000u);
                a4 += __uint_as_float(v0.z << 16);
                a5 += __uint_as_float(v0.z & 0xffff0000u);
                a6 += __uint_as_float(v0.w << 16);
                a7 += __uint_as_float(v0.w & 0xffff0000u);
            }
            float sc = 1.0f / fmaxf((float)m, 1.0f);  // mean fold at flush
            uint4 o;
            o.x = pk2(a0 * sc, a1 * sc);
            o.y = pk2(a2 * sc, a3 * sc);
            o.z = pk2(a4 * sc, a5 * sc);
            o.w = pk2(a6 * sc, a7 * sc);
            *(uint4*)(&accum[bb * APK + q8 * 4]) = o;  // group-owned write
        }
    }
    __syncthreads();

    // Stage 3: MFMA. A: m=lane&15 (node), k=g*8+j (+32*ks); B from wpk.
    // C/D: col=lane&15, row=(lane>>4)*4+i.
    const int ncol = lane & 15;
    const int g = lane >> 4;
    const int h = wv >> 2;            // relation half
    const int slice = wv & 3;         // output col slice (16 cols)
    f32x4 acc = {0.0f, 0.0f, 0.0f, 0.0f};

#pragma unroll
    for (int rr = 0; rr < 4; ++rr) {
        const int r = h * 4 + rr;
        const int bb = r * TS + ncol;
#pragma unroll
        for (int ks = 0; ks < 2; ++ks) {
            uint4 a4 = *(const uint4*)(accum + bb * APK + ks * 16 + g * 4);
            uint4 b4 = wpk[((r * 2 + ks) * 4 + g) * 64 + slice * 16 + ncol];
            bf16x8 af = __builtin_bit_cast(bf16x8, a4);
            bf16x8 bf = __builtin_bit_cast(bf16x8, b4);
            acc = __builtin_amdgcn_mfma_f32_16x16x32_bf16(af, bf, acc, 0, 0, 0);
        }
    }
    if (h == 0) {  // root transform: A-frags straight from packed xb
        const unsigned* xr = xb + (size_t)(tile * TS + ncol) * (D / 2);
#pragma unroll
        for (int ks = 0; ks < 2; ++ks) {
            uint4 a4 = *(const uint4*)(xr + ks * 16 + g * 4);
            bf16x8 af = __builtin_bit_cast(bf16x8, a4);
            uint4 b4 = wpk[NWPK + (ks * 4 + g) * 64 + slice * 16 + ncol];
            bf16x8 bf = __builtin_bit_cast(bf16x8, b4);
            acc = __builtin_amdgcn_mfma_f32_16x16x32_bf16(af, bf, acc, 0, 0, 0);
        }
    }
    __syncthreads();                   // all accum reads done
    float* red = (float*)accum;        // alias reuse for cross-half reduction
    const int rrow = g * 4;
    if (h == 1) {
#pragma unroll
        for (int i = 0; i < 4; ++i)
            red[(slice * 16 + rrow + i) * RPAD + ncol] = acc[i];
    }
    __syncthreads();
    if (h == 0) {
        const float bv = bias[slice * 16 + ncol];
#pragma unroll
        for (int i = 0; i < 4; ++i) {
            float v = acc[i] + red[(slice * 16 + rrow + i) * RPAD + ncol] + bv;
            v = fmaxf(v, 0.0f);
            out[((size_t)tile * TS + rrow + i) * D + slice * 16 + ncol] = v;
        }
    }
}

extern "C" void kernel_launch(void* const* d_in, const int* in_sizes, int n_in,
                              void* d_out, int out_size, void* d_ws, size_t ws_size,
                              hipStream_t stream) {
    const float* x    = (const float*)d_in[0];
    const int*   ei   = (const int*)d_in[1];   // [2, NE]
    const int*   et   = (const int*)d_in[2];   // [NE]
    const float* W    = (const float*)d_in[3]; // [NR, D, D]
    const float* Wr   = (const float*)d_in[4]; // [D, D]
    const float* bias = (const float*)d_in[5]; // [D]
    float* out = (float*)d_out;                // [NN, D]

    // ws layout (ints, 16B-aligned blocks):
    // cursor[NT*16] | sorted[NT*CAP] | xb[NN*32] | wpk[(NWPK+NWPKR)*uint4]
    int* cursor = (int*)d_ws;
    size_t o1 = (size_t)NT * CSTRIDE;
    int* sorted = cursor + o1;
    size_t o2 = o1 + (size_t)NT * CAP;
    unsigned* xb = (unsigned*)(cursor + o2);
    size_t o3 = o2 + (size_t)NN * (D / 2);
    o3 = (o3 + 3) & ~(size_t)3;
    uint4* wpk = (uint4*)(cursor + o3);

    init_kernel<<<(NT + 255) / 256, 256, 0, stream>>>(cursor);
    setup_kernel<<<XPB + PPB, 256, 0, stream>>>(x, W, Wr, xb, wpk);
    scatter_kernel<<<NCH * 8, 256, 0, stream>>>(ei, et, cursor, sorted);
    fused_kernel<<<NT, 512, 0, stream>>>(xb, sorted, cursor, wpk, bias, out);
}

// Round 23
// 106.355 us; speedup vs baseline: 1.7161x; 1.4382x over previous
//
#include <hip/hip_runtime.h>

#define NN 100000
#define NE 1600000
#define D 64
#define NR 8
#define TS 16                  // dst-tile size (nodes per block)
#define NT (NN / TS)           // 6250 tiles, exact
#define APK 36                 // packed accum row stride (dwords): 32 data + 4 pad
#define RPAD 17                // reduction scratch pad (floats)
#define NB 128                 // (r, dst&15) bins per tile
#define CAP 512                // slots per tile segment
#define CSTRIDE 16             // cursor padding: 1 cursor per 64B line
#define BK 250                 // coarse buckets (25 tiles = 400 nodes each)
#define BKCAP 8192             // slots per bucket segment (mean 6400, +22 sigma)
#define P1CHUNK 4096           // edges per pass-1 block (16/thread)
#define P1B ((NE + P1CHUNK - 1) / P1CHUNK)  // 391
#define P2CHUNK 2048           // edges per pass-2 block chunk
#define NWPK 4096              // W bf16-frag entries (8r x 2ks x 4g x 64col)
#define NWPKR 512              // Wr entries (2ks x 4g x 64col)
#define XPB 12500              // xpack blocks (NN*D/2 / 256)
#define PPB 18                 // prepack blocks

typedef short bf16x8 __attribute__((ext_vector_type(8)));
typedef float f32x4 __attribute__((ext_vector_type(4)));

// f32 -> bf16 round-to-nearest-even (finite inputs only)
__device__ __forceinline__ unsigned f2bfu(float f) {
    unsigned u = __float_as_uint(f);
    return (u + 0x7fffu + ((u >> 16) & 1u)) >> 16;
}
__device__ __forceinline__ unsigned pk2(float a, float b) {
    return (f2bfu(a) & 0xffffu) | (f2bfu(b) << 16);
}

__global__ void init_kernel(int* __restrict__ cursor, int* __restrict__ bkCursor) {
    int i = blockIdx.x * blockDim.x + threadIdx.x;
    if (i < NT) cursor[(size_t)i * CSTRIDE] = i * CAP;
    if (i < BK) bkCursor[(size_t)i * CSTRIDE] = 0;
}

// Setup: xpack (x->bf16 packed rows) | prepack (W,Wr -> B-frag bf16)
__global__ void __launch_bounds__(256) setup_kernel(
    const float* __restrict__ x, const float* __restrict__ W,
    const float* __restrict__ Wr, unsigned* __restrict__ xb,
    uint4* __restrict__ wpk)
{
    const int b = blockIdx.x;
    const int tid = threadIdx.x;
    if (b < XPB) {
        int i = b * 256 + tid;                 // < NN*D/2 exactly
        float2 f = ((const float2*)x)[i];
        xb[i] = pk2(f.x, f.y);
    } else {
        int e = (b - XPB) * 256 + tid;
        if (e >= NWPK + NWPKR) return;
        const float* src;
        int col, row0;
        if (e < NWPK) {
            int r = e >> 9, ks = (e >> 8) & 1, g = (e >> 6) & 3;
            col = e & 63;
            src = W + (size_t)r * D * D;
            row0 = ks * 32 + g * 8;
        } else {
            int e2 = e - NWPK;
            int ks = (e2 >> 8) & 1, g = (e2 >> 6) & 3;
            col = e2 & 63;
            src = Wr;
            row0 = ks * 32 + g * 8;
        }
        float v[8];
#pragma unroll
        for (int j = 0; j < 8; ++j) v[j] = src[(size_t)(row0 + j) * D + col];
        uint4 o;
        o.x = pk2(v[0], v[1]); o.y = pk2(v[2], v[3]);
        o.z = pk2(v[4], v[5]); o.w = pk2(v[6], v[7]);
        wpk[e] = o;
    }
}

// Pass 1: partition edges into 250 coarse buckets (25 tiles each).
// LDS hist -> wave-0 scan -> LDS reorder -> ONE claim atomic per
// (block,bucket) -> coalesced run writes. rec = src|r<<17|(dst%400)<<20.
__global__ void __launch_bounds__(256) p1_kernel(
    const int* __restrict__ ei, const int* __restrict__ et,
    int* __restrict__ bkCursor, int* __restrict__ bkSeg)
{
    __shared__ int eseq[P1CHUNK];
    __shared__ unsigned char ebk[P1CHUNK];
    __shared__ int bh[BK], bst[BK], bcur[BK], gbase[BK];
    const int tid = threadIdx.x;
    const int lane = tid & 63;
    const int wv = tid >> 6;
    const int c0 = blockIdx.x * P1CHUNK;
    const int n = min(P1CHUNK, NE - c0);

    for (int i = tid; i < BK; i += 256) bh[i] = 0;
    __syncthreads();

    int rec[16], bkk[16];
#pragma unroll
    for (int k = 0; k < 16; ++k) {
        int e = c0 + tid + k * 256;
        bool ok = e < NE;
        int d = ok ? ei[NE + e] : 0;
        int s = ok ? ei[e] : 0;
        int r = ok ? et[e] : 0;
        unsigned bu = (unsigned)d / 400u;
        int dl = d - (int)bu * 400;
        rec[k] = s | (r << 17) | (dl << 20);
        bkk[k] = ok ? (int)bu : -1;
        if (ok) atomicAdd(&bh[bu], 1);
    }
    __syncthreads();
    if (wv == 0) {                  // 250-bin exclusive scan: 4 bins/lane
        int idx = lane * 4;
        int b0 = (idx + 0 < BK) ? bh[idx + 0] : 0;
        int b1 = (idx + 1 < BK) ? bh[idx + 1] : 0;
        int b2 = (idx + 2 < BK) ? bh[idx + 2] : 0;
        int b3 = (idx + 3 < BK) ? bh[idx + 3] : 0;
        int s = b0 + b1 + b2 + b3;
        int inc = s;
#pragma unroll
        for (int off = 1; off < 64; off <<= 1) {
            int u = __shfl_up(inc, off);
            if (lane >= off) inc += u;
        }
        int ex = inc - s;
        if (idx + 0 < BK) { bst[idx + 0] = ex; bcur[idx + 0] = ex; } ex += b0;
        if (idx + 1 < BK) { bst[idx + 1] = ex; bcur[idx + 1] = ex; } ex += b1;
        if (idx + 2 < BK) { bst[idx + 2] = ex; bcur[idx + 2] = ex; } ex += b2;
        if (idx + 3 < BK) { bst[idx + 3] = ex; bcur[idx + 3] = ex; }
    }
    __syncthreads();
#pragma unroll
    for (int k = 0; k < 16; ++k) {
        if (bkk[k] >= 0) {
            int p = atomicAdd(&bcur[bkk[k]], 1);
            eseq[p] = rec[k];
            ebk[p] = (unsigned char)bkk[k];
        }
    }
    __syncthreads();
    for (int i = tid; i < BK; i += 256) {
        int h = bh[i];
        gbase[i] = h ? atomicAdd(&bkCursor[(size_t)i * CSTRIDE], h) : 0;
    }
    __syncthreads();
#pragma unroll
    for (int k = 0; k < 16; ++k) {
        int j = tid + k * 256;
        if (j < n) {
            int bb = ebk[j];
            int pos = gbase[bb] + (j - bst[bb]);
            if (pos < BKCAP) bkSeg[(size_t)bb * BKCAP + pos] = eseq[j];
        }
    }
}

// Pass 2: per (bucket, chunk): coalesced read of bucket segment, 25-bin LDS
// sort by tile-local dst, 25 claim atomics, burst writes into sorted[] in
// exactly the layout fused_kernel expects.
__global__ void __launch_bounds__(256) p2_kernel(
    const int* __restrict__ bkCursor, const int* __restrict__ bkSeg,
    int* __restrict__ cursor, int* __restrict__ sorted)
{
    const int b = blockIdx.x >> 2;
    const int c = blockIdx.x & 3;
    int nb = bkCursor[(size_t)b * CSTRIDE];
    if (nb > BKCAP) nb = BKCAP;
    const int lo = c * P2CHUNK;
    if (lo >= nb) return;               // uniform across block
    const int hi = min(lo + P2CHUNK, nb);
    const int cnt = hi - lo;

    __shared__ int eseq2[P2CHUNK];
    __shared__ unsigned char etl[P2CHUNK];
    __shared__ int bh2[25], bst2[25], bcur2[25], gb2[25];
    const int tid = threadIdx.x;
    const int lane = tid & 63;
    const int wv = tid >> 6;

    if (tid < 25) bh2[tid] = 0;
    __syncthreads();

    int rec2[8], tl[8];
#pragma unroll
    for (int k = 0; k < 8; ++k) {
        int j = lo + tid + k * 256;
        bool ok = j < hi;
        int rv = ok ? bkSeg[(size_t)b * BKCAP + j] : 0;
        int dl = (rv >> 20) & 0x1FF;
        tl[k] = ok ? (dl >> 4) : -1;
        rec2[k] = (rv & 0xFFFFF) | ((dl & 15) << 20);
        if (ok) atomicAdd(&bh2[tl[k]], 1);
    }
    __syncthreads();
    if (wv == 0 && lane < 32) {         // 25-bin scan + per-tile claims
        int v = (lane < 25) ? bh2[lane] : 0;
        int inc = v;
#pragma unroll
        for (int off = 1; off < 32; off <<= 1) {
            int u = __shfl_up(inc, off);
            if (lane >= off) inc += u;
        }
        if (lane < 25) {
            int ex = inc - v;
            bst2[lane] = ex; bcur2[lane] = ex;
            int t = b * 25 + lane;
            gb2[lane] = v ? atomicAdd(&cursor[(size_t)t * CSTRIDE], v) : 0;
        }
    }
    __syncthreads();
#pragma unroll
    for (int k = 0; k < 8; ++k) {
        if (tl[k] >= 0) {
            int p = atomicAdd(&bcur2[tl[k]], 1);
            eseq2[p] = rec2[k];
            etl[p] = (unsigned char)tl[k];
        }
    }
    __syncthreads();
#pragma unroll
    for (int k = 0; k < 8; ++k) {
        int j = tid + k * 256;
        if (j < cnt) {
            int t5 = etl[j];
            int t = b * 25 + t5;
            int pos = gb2[t5] + (j - bst2[t5]);
            if (pos < t * CAP + CAP) sorted[pos] = eseq2[j];
        }
    }
}

// One block (8 waves, 512 thr) per dst-tile. Single-pass (csz<=512):
// Stage 1: in-LDS counting sort by bin=(r*16+t), wave-0 shfl prefix scan.
// Stage 2: 64 groups of 8 lanes; each group owns 2 bins (mean 4 edges).
//          Lane loads uint4 (8 dims), f32 accumulate; flush = scale+pack.
// Stage 3: MFMA (A from packed LDS rows, B from wpk, root A from xb).
__global__ void __launch_bounds__(512) fused_kernel(
    const unsigned* __restrict__ xb, const int* __restrict__ sorted,
    const int* __restrict__ cursor, const uint4* __restrict__ wpk,
    const float* __restrict__ bias, float* __restrict__ out)
{
    __shared__ unsigned accum[NB * APK];   // packed bf16 rows, bin=r*16+t
    __shared__ int eseq[CAP];
    __shared__ int bh[NB], bst[NB], bcur[NB];
    const int tid = threadIdx.x;
    const int lane = tid & 63;
    const int wv = tid >> 6;          // 0..7
    const int tile = blockIdx.x;

    int csz = cursor[(size_t)tile * CSTRIDE] - tile * CAP;  // issued early
    if (tid < NB) bh[tid] = 0;
    __syncthreads();

    if (csz > CAP) csz = CAP;
    int rec = 0, bin = 0;
    const bool have = tid < csz;
    if (have) {
        rec = sorted[tile * CAP + tid];
        bin = ((rec >> 17) & 7) * 16 + ((rec >> 20) & 15);
        atomicAdd(&bh[bin], 1);
    }
    __syncthreads();
    if (wv == 0) {                     // parallel 128-bin exclusive scan
        int b0 = bh[2 * lane], b1 = bh[2 * lane + 1];
        int s = b0 + b1;
        int inc = s;
#pragma unroll
        for (int off = 1; off < 64; off <<= 1) {
            int u = __shfl_up(inc, off);
            if (lane >= off) inc += u;
        }
        int excl = inc - s;
        bst[2 * lane] = excl;          bcur[2 * lane] = excl;
        bst[2 * lane + 1] = excl + b0; bcur[2 * lane + 1] = excl + b0;
    }
    __syncthreads();
    if (have) {
        int p = atomicAdd(&bcur[bin], 1);
        eseq[p] = rec;
    }
    __syncthreads();
    {
        const int grp8 = tid >> 3;     // 0..63
        const int q8 = tid & 7;        // uint4 slot in row (8 dims)
#pragma unroll
        for (int half = 0; half < 2; ++half) {
            const int bb = grp8 + half * 64;
            int m = bh[bb];
            int st = bst[bb];
            float a0=0.f,a1=0.f,a2=0.f,a3=0.f,a4=0.f,a5=0.f,a6=0.f,a7=0.f;
            int i = 0;
            for (; i + 1 < m; i += 2) {
                int s0 = eseq[st + i] & 0x1FFFF;
                int s1 = eseq[st + i + 1] & 0x1FFFF;
                uint4 v0 = *(const uint4*)(xb + (size_t)s0 * (D / 2) + q8 * 4);
                uint4 v1 = *(const uint4*)(xb + (size_t)s1 * (D / 2) + q8 * 4);
                a0 += __uint_as_float(v0.x << 16) + __uint_as_float(v1.x << 16);
                a1 += __uint_as_float(v0.x & 0xffff0000u) + __uint_as_float(v1.x & 0xffff0000u);
                a2 += __uint_as_float(v0.y << 16) + __uint_as_float(v1.y << 16);
                a3 += __uint_as_float(v0.y & 0xffff0000u) + __uint_as_float(v1.y & 0xffff0000u);
                a4 += __uint_as_float(v0.z << 16) + __uint_as_float(v1.z << 16);
                a5 += __uint_as_float(v0.z & 0xffff0000u) + __uint_as_float(v1.z & 0xffff0000u);
                a6 += __uint_as_float(v0.w << 16) + __uint_as_float(v1.w << 16);
                a7 += __uint_as_float(v0.w & 0xffff0000u) + __uint_as_float(v1.w & 0xffff0000u);
            }
            if (i < m) {
                int s0 = eseq[st + i] & 0x1FFFF;
                uint4 v0 = *(const uint4*)(xb + (size_t)s0 * (D / 2) + q8 * 4);
                a0 += __uint_as_float(v0.x << 16);
                a1 += __uint_as_float(v0.x & 0xffff0000u);
                a2 += __uint_as_float(v0.y << 16);
                a3 += __uint_as_float(v0.y & 0xffff0000u);
                a4 += __uint_as_float(v0.z << 16);
                a5 += __uint_as_float(v0.z & 0xffff0000u);
                a6 += __uint_as_float(v0.w << 16);
                a7 += __uint_as_float(v0.w & 0xffff0000u);
            }
            float sc = 1.0f / fmaxf((float)m, 1.0f);  // mean fold at flush
            uint4 o;
            o.x = pk2(a0 * sc, a1 * sc);
            o.y = pk2(a2 * sc, a3 * sc);
            o.z = pk2(a4 * sc, a5 * sc);
            o.w = pk2(a6 * sc, a7 * sc);
            *(uint4*)(&accum[bb * APK + q8 * 4]) = o;  // group-owned write
        }
    }
    __syncthreads();

    // Stage 3: MFMA. A: m=lane&15 (node), k=g*8+j (+32*ks); B from wpk.
    // C/D: col=lane&15, row=(lane>>4)*4+i.
    const int ncol = lane & 15;
    const int g = lane >> 4;
    const int h = wv >> 2;            // relation half
    const int slice = wv & 3;         // output col slice (16 cols)
    f32x4 acc = {0.0f, 0.0f, 0.0f, 0.0f};

#pragma unroll
    for (int rr = 0; rr < 4; ++rr) {
        const int r = h * 4 + rr;
        const int bb = r * TS + ncol;
#pragma unroll
        for (int ks = 0; ks < 2; ++ks) {
            uint4 a4 = *(const uint4*)(accum + bb * APK + ks * 16 + g * 4);
            uint4 b4 = wpk[((r * 2 + ks) * 4 + g) * 64 + slice * 16 + ncol];
            bf16x8 af = __builtin_bit_cast(bf16x8, a4);
            bf16x8 bf = __builtin_bit_cast(bf16x8, b4);
            acc = __builtin_amdgcn_mfma_f32_16x16x32_bf16(af, bf, acc, 0, 0, 0);
        }
    }
    if (h == 0) {  // root transform: A-frags straight from packed xb
        const unsigned* xr = xb + (size_t)(tile * TS + ncol) * (D / 2);
#pragma unroll
        for (int ks = 0; ks < 2; ++ks) {
            uint4 a4 = *(const uint4*)(xr + ks * 16 + g * 4);
            bf16x8 af = __builtin_bit_cast(bf16x8, a4);
            uint4 b4 = wpk[NWPK + (ks * 4 + g) * 64 + slice * 16 + ncol];
            bf16x8 bf = __builtin_bit_cast(bf16x8, b4);
            acc = __builtin_amdgcn_mfma_f32_16x16x32_bf16(af, bf, acc, 0, 0, 0);
        }
    }
    __syncthreads();                   // all accum reads done
    float* red = (float*)accum;        // alias reuse for cross-half reduction
    const int rrow = g * 4;
    if (h == 1) {
#pragma unroll
        for (int i = 0; i < 4; ++i)
            red[(slice * 16 + rrow + i) * RPAD + ncol] = acc[i];
    }
    __syncthreads();
    if (h == 0) {
        const float bv = bias[slice * 16 + ncol];
#pragma unroll
        for (int i = 0; i < 4; ++i) {
            float v = acc[i] + red[(slice * 16 + rrow + i) * RPAD + ncol] + bv;
            v = fmaxf(v, 0.0f);
            out[((size_t)tile * TS + rrow + i) * D + slice * 16 + ncol] = v;
        }
    }
}

extern "C" void kernel_launch(void* const* d_in, const int* in_sizes, int n_in,
                              void* d_out, int out_size, void* d_ws, size_t ws_size,
                              hipStream_t stream) {
    const float* x    = (const float*)d_in[0];
    const int*   ei   = (const int*)d_in[1];   // [2, NE]
    const int*   et   = (const int*)d_in[2];   // [NE]
    const float* W    = (const float*)d_in[3]; // [NR, D, D]
    const float* Wr   = (const float*)d_in[4]; // [D, D]
    const float* bias = (const float*)d_in[5]; // [D]
    float* out = (float*)d_out;                // [NN, D]

    // ws layout (ints, 16B-aligned blocks): cursor[NT*16] | bkCursor[BK*16] |
    // sorted[NT*CAP] | bkSeg[BK*BKCAP] | xb[NN*32] | wpk[(NWPK+NWPKR)*uint4]
    int* cursor = (int*)d_ws;
    size_t o1 = (size_t)NT * CSTRIDE;
    int* bkCursor = cursor + o1;
    size_t o2 = o1 + (size_t)BK * CSTRIDE;
    int* sorted = cursor + o2;
    size_t o3 = o2 + (size_t)NT * CAP;
    int* bkSeg = cursor + o3;
    size_t o4 = o3 + (size_t)BK * BKCAP;
    unsigned* xb = (unsigned*)(cursor + o4);
    size_t o5 = o4 + (size_t)NN * (D / 2);
    o5 = (o5 + 3) & ~(size_t)3;
    uint4* wpk = (uint4*)(cursor + o5);

    init_kernel<<<(NT + 255) / 256, 256, 0, stream>>>(cursor, bkCursor);
    setup_kernel<<<XPB + PPB, 256, 0, stream>>>(x, W, Wr, xb, wpk);
    p1_kernel<<<P1B, 256, 0, stream>>>(ei, et, bkCursor, bkSeg);
    p2_kernel<<<BK * 4, 256, 0, stream>>>(bkCursor, bkSeg, cursor, sorted);
    fused_kernel<<<NT, 512, 0, stream>>>(xb, sorted, cursor, wpk, bias, out);
}

// Round 24
// 99.062 us; speedup vs baseline: 1.8425x; 1.0736x over previous
//
#include <hip/hip_runtime.h>

#define NN 100000
#define NE 1600000
#define D 64
#define NR 8
#define TS 16                  // dst-tile size (nodes per block)
#define NT (NN / TS)           // 6250 tiles, exact
#define APK 36                 // packed accum row stride (dwords): 32 data + 4 pad
#define RPAD 17                // reduction scratch pad (floats)
#define NB 128                 // (r, dst&15) bins per tile
#define CAP 512                // slots per tile segment
#define CSTRIDE 16             // cursor padding: 1 cursor per 64B line
#define BK 250                 // coarse buckets (25 tiles = 400 nodes each)
#define BKCAP 8192             // slots per bucket segment (mean 6400, +22 sigma)
#define P1CHUNK 4096           // edges per pass-1 block (16/thread)
#define P1B ((NE + P1CHUNK - 1) / P1CHUNK)  // 391
#define P2CHUNK 2048           // edges per pass-2 block chunk
#define NWPK 4096              // W bf16-frag entries (8r x 2ks x 4g x 64col)
#define NWPKR 512              // Wr entries (2ks x 4g x 64col)
#define XPB 12500              // xpack blocks (NN*D/2 / 256)
#define PPB 18                 // prepack blocks

typedef short bf16x8 __attribute__((ext_vector_type(8)));
typedef float f32x4 __attribute__((ext_vector_type(4)));

// f32 -> bf16 round-to-nearest-even (finite inputs only)
__device__ __forceinline__ unsigned f2bfu(float f) {
    unsigned u = __float_as_uint(f);
    return (u + 0x7fffu + ((u >> 16) & 1u)) >> 16;
}
__device__ __forceinline__ unsigned pk2(float a, float b) {
    return (f2bfu(a) & 0xffffu) | (f2bfu(b) << 16);
}

__global__ void init_kernel(int* __restrict__ cursor, int* __restrict__ bkCursor) {
    int i = blockIdx.x * blockDim.x + threadIdx.x;
    if (i < NT) cursor[(size_t)i * CSTRIDE] = i * CAP;
    if (i < BK) bkCursor[(size_t)i * CSTRIDE] = 0;
}

// Combo dispatch: [0,P1B) radix pass 1 | [P1B,+XPB) xpack | [+PPB) prepack.
// p1 and setup are data-independent; one dispatch overlaps their traffic.
__global__ void __launch_bounds__(256) combo_kernel(
    const int* __restrict__ ei, const int* __restrict__ et,
    const float* __restrict__ x, const float* __restrict__ W,
    const float* __restrict__ Wr, int* __restrict__ bkCursor,
    int* __restrict__ bkSeg, unsigned* __restrict__ xb,
    uint4* __restrict__ wpk)
{
    __shared__ int eseq[P1CHUNK];
    __shared__ unsigned char ebk[P1CHUNK];
    __shared__ int bh[BK], bst[BK], bcur[BK], gbase[BK];
    const int blk = blockIdx.x;
    const int tid = threadIdx.x;

    if (blk >= P1B) {
        int b2 = blk - P1B;
        if (b2 < XPB) {
            int i = b2 * 256 + tid;            // < NN*D/2 exactly
            float2 f = ((const float2*)x)[i];
            xb[i] = pk2(f.x, f.y);
        } else {
            int e = (b2 - XPB) * 256 + tid;
            if (e >= NWPK + NWPKR) return;
            const float* src;
            int col, row0;
            if (e < NWPK) {
                int r = e >> 9, ks = (e >> 8) & 1, g = (e >> 6) & 3;
                col = e & 63;
                src = W + (size_t)r * D * D;
                row0 = ks * 32 + g * 8;
            } else {
                int e2 = e - NWPK;
                int ks = (e2 >> 8) & 1, g = (e2 >> 6) & 3;
                col = e2 & 63;
                src = Wr;
                row0 = ks * 32 + g * 8;
            }
            float v[8];
#pragma unroll
            for (int j = 0; j < 8; ++j) v[j] = src[(size_t)(row0 + j) * D + col];
            uint4 o;
            o.x = pk2(v[0], v[1]); o.y = pk2(v[2], v[3]);
            o.z = pk2(v[4], v[5]); o.w = pk2(v[6], v[7]);
            wpk[e] = o;
        }
        return;
    }

    // ---- radix pass 1: partition into 250 coarse buckets ----
    const int lane = tid & 63;
    const int wv = tid >> 6;
    const int c0 = blk * P1CHUNK;
    const int n = min(P1CHUNK, NE - c0);

    for (int i = tid; i < BK; i += 256) bh[i] = 0;
    __syncthreads();

    int rec[16], bkk[16];
#pragma unroll
    for (int k = 0; k < 16; ++k) {
        int e = c0 + tid + k * 256;
        bool ok = e < NE;
        int d = ok ? ei[NE + e] : 0;
        int s = ok ? ei[e] : 0;
        int r = ok ? et[e] : 0;
        unsigned bu = (unsigned)d / 400u;
        int dl = d - (int)bu * 400;
        rec[k] = s | (r << 17) | (dl << 20);
        bkk[k] = ok ? (int)bu : -1;
        if (ok) atomicAdd(&bh[bu], 1);
    }
    __syncthreads();
    if (wv == 0) {                  // 250-bin exclusive scan: 4 bins/lane
        int idx = lane * 4;
        int b0 = (idx + 0 < BK) ? bh[idx + 0] : 0;
        int b1 = (idx + 1 < BK) ? bh[idx + 1] : 0;
        int b2 = (idx + 2 < BK) ? bh[idx + 2] : 0;
        int b3 = (idx + 3 < BK) ? bh[idx + 3] : 0;
        int s = b0 + b1 + b2 + b3;
        int inc = s;
#pragma unroll
        for (int off = 1; off < 64; off <<= 1) {
            int u = __shfl_up(inc, off);
            if (lane >= off) inc += u;
        }
        int ex = inc - s;
        if (idx + 0 < BK) { bst[idx + 0] = ex; bcur[idx + 0] = ex; } ex += b0;
        if (idx + 1 < BK) { bst[idx + 1] = ex; bcur[idx + 1] = ex; } ex += b1;
        if (idx + 2 < BK) { bst[idx + 2] = ex; bcur[idx + 2] = ex; } ex += b2;
        if (idx + 3 < BK) { bst[idx + 3] = ex; bcur[idx + 3] = ex; }
    }
    __syncthreads();
#pragma unroll
    for (int k = 0; k < 16; ++k) {
        if (bkk[k] >= 0) {
            int p = atomicAdd(&bcur[bkk[k]], 1);
            eseq[p] = rec[k];
            ebk[p] = (unsigned char)bkk[k];
        }
    }
    __syncthreads();
    for (int i = tid; i < BK; i += 256) {
        int h = bh[i];
        gbase[i] = h ? atomicAdd(&bkCursor[(size_t)i * CSTRIDE], h) : 0;
    }
    __syncthreads();
#pragma unroll
    for (int k = 0; k < 16; ++k) {
        int j = tid + k * 256;
        if (j < n) {
            int bb = ebk[j];
            int pos = gbase[bb] + (j - bst[bb]);
            if (pos < BKCAP) bkSeg[(size_t)bb * BKCAP + pos] = eseq[j];
        }
    }
}

// Pass 2: per (bucket, chunk): coalesced read of bucket segment, 25-bin LDS
// sort by tile-local dst, 25 claim atomics, burst writes into sorted[].
__global__ void __launch_bounds__(256) p2_kernel(
    const int* __restrict__ bkCursor, const int* __restrict__ bkSeg,
    int* __restrict__ cursor, int* __restrict__ sorted)
{
    const int b = blockIdx.x >> 2;
    const int c = blockIdx.x & 3;
    int nb = bkCursor[(size_t)b * CSTRIDE];
    if (nb > BKCAP) nb = BKCAP;
    const int lo = c * P2CHUNK;
    if (lo >= nb) return;               // uniform across block
    const int hi = min(lo + P2CHUNK, nb);
    const int cnt = hi - lo;

    __shared__ int eseq2[P2CHUNK];
    __shared__ unsigned char etl[P2CHUNK];
    __shared__ int bh2[25], bst2[25], bcur2[25], gb2[25];
    const int tid = threadIdx.x;
    const int lane = tid & 63;
    const int wv = tid >> 6;

    if (tid < 25) bh2[tid] = 0;
    __syncthreads();

    int rec2[8], tl[8];
#pragma unroll
    for (int k = 0; k < 8; ++k) {
        int j = lo + tid + k * 256;
        bool ok = j < hi;
        int rv = ok ? bkSeg[(size_t)b * BKCAP + j] : 0;
        int dl = (rv >> 20) & 0x1FF;
        tl[k] = ok ? (dl >> 4) : -1;
        rec2[k] = (rv & 0xFFFFF) | ((dl & 15) << 20);
        if (ok) atomicAdd(&bh2[tl[k]], 1);
    }
    __syncthreads();
    if (wv == 0 && lane < 32) {         // 25-bin scan + per-tile claims
        int v = (lane < 25) ? bh2[lane] : 0;
        int inc = v;
#pragma unroll
        for (int off = 1; off < 32; off <<= 1) {
            int u = __shfl_up(inc, off);
            if (lane >= off) inc += u;
        }
        if (lane < 25) {
            int ex = inc - v;
            bst2[lane] = ex; bcur2[lane] = ex;
            int t = b * 25 + lane;
            gb2[lane] = v ? atomicAdd(&cursor[(size_t)t * CSTRIDE], v) : 0;
        }
    }
    __syncthreads();
#pragma unroll
    for (int k = 0; k < 8; ++k) {
        if (tl[k] >= 0) {
            int p = atomicAdd(&bcur2[tl[k]], 1);
            eseq2[p] = rec2[k];
            etl[p] = (unsigned char)tl[k];
        }
    }
    __syncthreads();
#pragma unroll
    for (int k = 0; k < 8; ++k) {
        int j = tid + k * 256;
        if (j < cnt) {
            int t5 = etl[j];
            int t = b * 25 + t5;
            int pos = gb2[t5] + (j - bst2[t5]);
            if (pos < t * CAP + CAP) sorted[pos] = eseq2[j];
        }
    }
}

// One block (8 waves, 512 thr) per dst-tile. Single-pass (csz<=512):
// Stage 1: in-LDS counting sort by bin=(r*16+t), wave-0 shfl prefix scan.
// Stage 2: 64 groups of 8 lanes; each group owns 2 bins (mean 4 edges).
//          Lane loads uint4 (8 dims), f32 accumulate; flush = scale+pack.
// Stage 3: MFMA (A from packed LDS rows, B from wpk, root A prefetched).
__global__ void __launch_bounds__(512) fused_kernel(
    const unsigned* __restrict__ xb, const int* __restrict__ sorted,
    const int* __restrict__ cursor, const uint4* __restrict__ wpk,
    const float* __restrict__ bias, float* __restrict__ out)
{
    __shared__ unsigned accum[NB * APK];   // packed bf16 rows, bin=r*16+t
    __shared__ int eseq[CAP];
    __shared__ int bh[NB], bst[NB], bcur[NB];
    const int tid = threadIdx.x;
    const int lane = tid & 63;
    const int wv = tid >> 6;          // 0..7
    const int tile = blockIdx.x;

    int csz = cursor[(size_t)tile * CSTRIDE] - tile * CAP;  // issued early
    // prefetch root A-fragments (used by h==0 waves in stage 3)
    const unsigned* xr = xb + (size_t)(tile * TS + (lane & 15)) * (D / 2);
    const int gpre = lane >> 4;
    uint4 ra0 = *(const uint4*)(xr + 0 * 16 + gpre * 4);
    uint4 ra1 = *(const uint4*)(xr + 1 * 16 + gpre * 4);

    if (tid < NB) bh[tid] = 0;
    __syncthreads();

    if (csz > CAP) csz = CAP;
    int rec = 0, bin = 0;
    const bool have = tid < csz;
    if (have) {
        rec = sorted[tile * CAP + tid];
        bin = ((rec >> 17) & 7) * 16 + ((rec >> 20) & 15);
        atomicAdd(&bh[bin], 1);
    }
    __syncthreads();
    if (wv == 0) {                     // parallel 128-bin exclusive scan
        int b0 = bh[2 * lane], b1 = bh[2 * lane + 1];
        int s = b0 + b1;
        int inc = s;
#pragma unroll
        for (int off = 1; off < 64; off <<= 1) {
            int u = __shfl_up(inc, off);
            if (lane >= off) inc += u;
        }
        int excl = inc - s;
        bst[2 * lane] = excl;          bcur[2 * lane] = excl;
        bst[2 * lane + 1] = excl + b0; bcur[2 * lane + 1] = excl + b0;
    }
    __syncthreads();
    if (have) {
        int p = atomicAdd(&bcur[bin], 1);
        eseq[p] = rec;
    }
    __syncthreads();
    {
        const int grp8 = tid >> 3;     // 0..63
        const int q8 = tid & 7;        // uint4 slot in row (8 dims)
#pragma unroll
        for (int half = 0; half < 2; ++half) {
            const int bb = grp8 + half * 64;
            int m = bh[bb];
            int st = bst[bb];
            float a0=0.f,a1=0.f,a2=0.f,a3=0.f,a4=0.f,a5=0.f,a6=0.f,a7=0.f;
            int i = 0;
            for (; i + 1 < m; i += 2) {
                int s0 = eseq[st + i] & 0x1FFFF;
                int s1 = eseq[st + i + 1] & 0x1FFFF;
                uint4 v0 = *(const uint4*)(xb + (size_t)s0 * (D / 2) + q8 * 4);
                uint4 v1 = *(const uint4*)(xb + (size_t)s1 * (D / 2) + q8 * 4);
                a0 += __uint_as_float(v0.x << 16) + __uint_as_float(v1.x << 16);
                a1 += __uint_as_float(v0.x & 0xffff0000u) + __uint_as_float(v1.x & 0xffff0000u);
                a2 += __uint_as_float(v0.y << 16) + __uint_as_float(v1.y << 16);
                a3 += __uint_as_float(v0.y & 0xffff0000u) + __uint_as_float(v1.y & 0xffff0000u);
                a4 += __uint_as_float(v0.z << 16) + __uint_as_float(v1.z << 16);
                a5 += __uint_as_float(v0.z & 0xffff0000u) + __uint_as_float(v1.z & 0xffff0000u);
                a6 += __uint_as_float(v0.w << 16) + __uint_as_float(v1.w << 16);
                a7 += __uint_as_float(v0.w & 0xffff0000u) + __uint_as_float(v1.w & 0xffff0000u);
            }
            if (i < m) {
                int s0 = eseq[st + i] & 0x1FFFF;
                uint4 v0 = *(const uint4*)(xb + (size_t)s0 * (D / 2) + q8 * 4);
                a0 += __uint_as_float(v0.x << 16);
                a1 += __uint_as_float(v0.x & 0xffff0000u);
                a2 += __uint_as_float(v0.y << 16);
                a3 += __uint_as_float(v0.y & 0xffff0000u);
                a4 += __uint_as_float(v0.z << 16);
                a5 += __uint_as_float(v0.z & 0xffff0000u);
                a6 += __uint_as_float(v0.w << 16);
                a7 += __uint_as_float(v0.w & 0xffff0000u);
            }
            float sc = 1.0f / fmaxf((float)m, 1.0f);  // mean fold at flush
            uint4 o;
            o.x = pk2(a0 * sc, a1 * sc);
            o.y = pk2(a2 * sc, a3 * sc);
            o.z = pk2(a4 * sc, a5 * sc);
            o.w = pk2(a6 * sc, a7 * sc);
            *(uint4*)(&accum[bb * APK + q8 * 4]) = o;  // group-owned write
        }
    }
    __syncthreads();

    // Stage 3: MFMA. A: m=lane&15 (node), k=g*8+j (+32*ks); B from wpk.
    // C/D: col=lane&15, row=(lane>>4)*4+i.
    const int ncol = lane & 15;
    const int g = lane >> 4;
    const int h = wv >> 2;            // relation half
    const int slice = wv & 3;         // output col slice (16 cols)
    f32x4 acc = {0.0f, 0.0f, 0.0f, 0.0f};

#pragma unroll
    for (int rr = 0; rr < 4; ++rr) {
        const int r = h * 4 + rr;
        const int bb = r * TS + ncol;
#pragma unroll
        for (int ks = 0; ks < 2; ++ks) {
            uint4 a4 = *(const uint4*)(accum + bb * APK + ks * 16 + g * 4);
            uint4 b4 = wpk[((r * 2 + ks) * 4 + g) * 64 + slice * 16 + ncol];
            bf16x8 af = __builtin_bit_cast(bf16x8, a4);
            bf16x8 bf = __builtin_bit_cast(bf16x8, b4);
            acc = __builtin_amdgcn_mfma_f32_16x16x32_bf16(af, bf, acc, 0, 0, 0);
        }
    }
    if (h == 0) {  // root transform: prefetched A-frags
#pragma unroll
        for (int ks = 0; ks < 2; ++ks) {
            uint4 a4 = (ks == 0) ? ra0 : ra1;
            bf16x8 af = __builtin_bit_cast(bf16x8, a4);
            uint4 b4 = wpk[NWPK + (ks * 4 + g) * 64 + slice * 16 + ncol];
            bf16x8 bf = __builtin_bit_cast(bf16x8, b4);
            acc = __builtin_amdgcn_mfma_f32_16x16x32_bf16(af, bf, acc, 0, 0, 0);
        }
    }
    __syncthreads();                   // all accum reads done
    float* red = (float*)accum;        // alias reuse for cross-half reduction
    const int rrow = g * 4;
    if (h == 1) {
#pragma unroll
        for (int i = 0; i < 4; ++i)
            red[(slice * 16 + rrow + i) * RPAD + ncol] = acc[i];
    }
    __syncthreads();
    if (h == 0) {
        const float bv = bias[slice * 16 + ncol];
#pragma unroll
        for (int i = 0; i < 4; ++i) {
            float v = acc[i] + red[(slice * 16 + rrow + i) * RPAD + ncol] + bv;
            v = fmaxf(v, 0.0f);
            out[((size_t)tile * TS + rrow + i) * D + slice * 16 + ncol] = v;
        }
    }
}

extern "C" void kernel_launch(void* const* d_in, const int* in_sizes, int n_in,
                              void* d_out, int out_size, void* d_ws, size_t ws_size,
                              hipStream_t stream) {
    const float* x    = (const float*)d_in[0];
    const int*   ei   = (const int*)d_in[1];   // [2, NE]
    const int*   et   = (const int*)d_in[2];   // [NE]
    const float* W    = (const float*)d_in[3]; // [NR, D, D]
    const float* Wr   = (const float*)d_in[4]; // [D, D]
    const float* bias = (const float*)d_in[5]; // [D]
    float* out = (float*)d_out;                // [NN, D]

    // ws layout (ints, 16B-aligned blocks): cursor[NT*16] | bkCursor[BK*16] |
    // sorted[NT*CAP] | bkSeg[BK*BKCAP] | xb[NN*32] | wpk[(NWPK+NWPKR)*uint4]
    int* cursor = (int*)d_ws;
    size_t o1 = (size_t)NT * CSTRIDE;
    int* bkCursor = cursor + o1;
    size_t o2 = o1 + (size_t)BK * CSTRIDE;
    int* sorted = cursor + o2;
    size_t o3 = o2 + (size_t)NT * CAP;
    int* bkSeg = cursor + o3;
    size_t o4 = o3 + (size_t)BK * BKCAP;
    unsigned* xb = (unsigned*)(cursor + o4);
    size_t o5 = o4 + (size_t)NN * (D / 2);
    o5 = (o5 + 3) & ~(size_t)3;
    uint4* wpk = (uint4*)(cursor + o5);

    init_kernel<<<(NT + 255) / 256, 256, 0, stream>>>(cursor, bkCursor);
    combo_kernel<<<P1B + XPB + PPB, 256, 0, stream>>>(ei, et, x, W, Wr,
                                                      bkCursor, bkSeg, xb, wpk);
    p2_kernel<<<BK * 4, 256, 0, stream>>>(bkCursor, bkSeg, cursor, sorted);
    fused_kernel<<<NT, 512, 0, stream>>>(xb, sorted, cursor, wpk, bias, out);
}